// Round 8
// baseline (270.412 us; speedup 1.0000x reference)
//
#include <hip/hip_runtime.h>
#include <hip/hip_bf16.h>
#include <hip/hip_fp16.h>

#define D 64
#define K3E 4096

// Edge word packing (requires N <= 65536, V <= 128 — true for this problem):
//   bits [0:15]  = src node
//   bits [16:22] = x[src]   (vocab id)
//   bits [23:30] = dst & 255 (node index within its 256-node bucket)

// ===== fused: per-bucket histogram + (last block) scan + embW GEMM tiles =====
// grid = 256 count blocks + ceil(V/64) gemm blocks. Count blocks use the
// last-block-done pattern (device-scope atomics + threadfence) so the scan
// runs in-kernel; gemm blocks are independent.

__global__ __launch_bounds__(256) void count_scan_emb_kernel(
    const int* __restrict__ dst, int E,
    int* __restrict__ bucketCount, int* __restrict__ bucketBase,
    int* __restrict__ bucketCursor, int* __restrict__ doneCtr,
    const float* __restrict__ emb, const float* __restrict__ W1,
    float* __restrict__ embW, int V)
{
    __shared__ union SM {
        struct { float At[64][68]; float Ws[64][64]; } g;
        struct { int hist[256]; int sc[256]; int isLast; } c;
    } sm;
    int t = threadIdx.x;

    if (blockIdx.x >= 256) {
        // ---- embW tile: rows r0..r0+63 of embW = emb @ W1 ----
        int r0 = (blockIdx.x - 256) * 64;
        const float4* wv = (const float4*)W1;
        float4* s1 = (float4*)&sm.g.Ws[0][0];
        for (int i = t; i < 1024; i += 256) s1[i] = wv[i];
        for (int i = t; i < 1024; i += 256) {
            int r = i >> 4, c4 = i & 15;
            int gr = r0 + r; if (gr >= V) gr = V - 1;
            float4 v = ((const float4*)(emb + (size_t)gr * D))[c4];
            float* dp = &sm.g.At[r][c4 * 4];
            dp[0] = v.x; dp[1] = v.y; dp[2] = v.z; dp[3] = v.w;
        }
        __syncthreads();
        int cg = t & 15, rg = t >> 4;
        float acc[4][4] = {{0.f}};
        for (int k0 = 0; k0 < 64; k0 += 4) {
            float4 a[4], w[4];
#pragma unroll
            for (int i = 0; i < 4; ++i) a[i] = *(const float4*)&sm.g.At[4 * rg + i][k0];
#pragma unroll
            for (int j = 0; j < 4; ++j) w[j] = *(const float4*)&sm.g.Ws[k0 + j][cg * 4];
#pragma unroll
            for (int i = 0; i < 4; ++i) {
                float av[4] = {a[i].x, a[i].y, a[i].z, a[i].w};
#pragma unroll
                for (int kk = 0; kk < 4; ++kk) {
                    acc[i][0] += av[kk] * w[kk].x;
                    acc[i][1] += av[kk] * w[kk].y;
                    acc[i][2] += av[kk] * w[kk].z;
                    acc[i][3] += av[kk] * w[kk].w;
                }
            }
        }
#pragma unroll
        for (int i = 0; i < 4; ++i) {
            int gr = r0 + 4 * rg + i;
            if (gr < V) {
                float4 o;
                o.x = acc[i][0]; o.y = acc[i][1]; o.z = acc[i][2]; o.w = acc[i][3];
                ((float4*)(embW + (size_t)gr * D))[cg] = o;
            }
        }
        return;
    }

    // ---- count phase (blocks 0..255) ----
    sm.c.hist[t] = 0;
    __syncthreads();
    for (int e = blockIdx.x * 256 + t; e < E; e += 256 * 256)
        atomicAdd(&sm.c.hist[dst[e] >> 8], 1);
    __syncthreads();
    int c = sm.c.hist[t];
    if (c) atomicAdd(&bucketCount[t], c);
    __threadfence();
    __syncthreads();
    if (t == 0) sm.c.isLast = (atomicAdd(doneCtr, 1) == 255);
    __syncthreads();
    if (!sm.c.isLast) return;

    // ---- scan phase (last count block only; all adds globally visible) ----
    __threadfence();
    int v = bucketCount[t];
    sm.c.sc[t] = v;
    __syncthreads();
    for (int off = 1; off < 256; off <<= 1) {
        int w = (t >= off) ? sm.c.sc[t - off] : 0;
        __syncthreads();
        sm.c.sc[t] += w;
        __syncthreads();
    }
    int excl = sm.c.sc[t] - v;
    bucketBase[t] = excl;
    bucketCursor[t] = excl;
    if (t == 255) bucketBase[256] = sm.c.sc[t];
}

// ================= scatter packed edges into bucket regions =================

__global__ __launch_bounds__(256) void scatter_kernel(const int* __restrict__ src,
                                                      const int* __restrict__ dst,
                                                      const int* __restrict__ x,
                                                      int* __restrict__ bucketCursor,
                                                      int* __restrict__ ebuf, int E) {
    __shared__ int uu[K3E];
    __shared__ unsigned char bb[K3E];
    __shared__ int hist[256];
    __shared__ int resBase[256];
    int t = threadIdx.x;
    hist[t] = 0;
    __syncthreads();
    int e0 = blockIdx.x * K3E;
    int cnt = E - e0; if (cnt > K3E) cnt = K3E;
    for (int i = t; i < cnt; i += 256) {
        int e = e0 + i;
        int s = src[e];
        int d = dst[e];
        int xs = x[s];
        uu[i] = s | (xs << 16) | ((d & 255) << 23);
        int b = d >> 8;
        bb[i] = (unsigned char)b;
        atomicAdd(&hist[b], 1);
    }
    __syncthreads();
    int c = hist[t];
    if (c) resBase[t] = atomicAdd(&bucketCursor[t], c);
    __syncthreads();
    hist[t] = 0;
    __syncthreads();
    for (int i = t; i < cnt; i += 256) {
        int b = bb[i];
        int r = atomicAdd(&hist[b], 1);
        ebuf[resBase[b] + r] = uu[i];
    }
}

// ================= per-bucket exact CSR =================

__global__ __launch_bounds__(256) void csr_kernel(const int* __restrict__ ebuf,
                                                  const int* __restrict__ bucketBase,
                                                  int* __restrict__ rowptr, int* __restrict__ col,
                                                  int N, int E) {
    __shared__ int hist[256];
    __shared__ int sc[256];
    int b = blockIdx.x, t = threadIdx.x;
    int base = bucketBase[b], endb = bucketBase[b + 1];
    int m = endb - base;
    hist[t] = 0;
    __syncthreads();
    for (int i = t; i < m; i += 256)
        atomicAdd(&hist[(ebuf[base + i] >> 23) & 255], 1);
    __syncthreads();
    int v = hist[t];
    sc[t] = v;
    __syncthreads();
    for (int off = 1; off < 256; off <<= 1) {
        int w = (t >= off) ? sc[t - off] : 0;
        __syncthreads();
        sc[t] += w;
        __syncthreads();
    }
    int excl = sc[t] - v;
    int node = (b << 8) + t;
    if (node < N) rowptr[node] = base + excl;
    if (b == gridDim.x - 1 && t == 0) rowptr[N] = E;
    __syncthreads();
    hist[t] = excl;   // running local cursor
    __syncthreads();
    for (int i = t; i < m; i += 256) {
        int u = ebuf[base + i];
        int dl = (u >> 23) & 255;
        int r = atomicAdd(&hist[dl], 1);
        col[base + r] = u;
    }
}

// ===== fp16-in / fp16-out GEMM (fp32 LDS + fp32 accumulate), optional dual output =====

__global__ __launch_bounds__(256) void gemm64h_kernel(
    const __half* __restrict__ in, int nrows,
    const float* __restrict__ W1, const float* __restrict__ W2,
    const float* __restrict__ bias, int do_relu,
    __half* __restrict__ out1, __half* __restrict__ out2)
{
    __shared__ float At[64][68];
    __shared__ float Ws1[64][64];
    __shared__ float Ws2[64][64];
    int tid = threadIdx.x;
    {
        const float4* w1v = (const float4*)W1;
        float4* s1 = (float4*)&Ws1[0][0];
        for (int i = tid; i < 1024; i += 256) s1[i] = w1v[i];
        if (W2) {
            const float4* w2v = (const float4*)W2;
            float4* s2 = (float4*)&Ws2[0][0];
            for (int i = tid; i < 1024; i += 256) s2[i] = w2v[i];
        }
    }
    int r0 = blockIdx.x * 64;
    for (int i = tid; i < 512; i += 256) {
        int r = i >> 3, c8 = i & 7;
        int gr = r0 + r; if (gr >= nrows) gr = nrows - 1;
        float4 hv = ((const float4*)(in + (size_t)gr * D))[c8];
        const __half2* hp = (const __half2*)&hv;
        float* dp = &At[r][c8 * 8];
        float2 f;
        f = __half22float2(hp[0]); dp[0] = f.x; dp[1] = f.y;
        f = __half22float2(hp[1]); dp[2] = f.x; dp[3] = f.y;
        f = __half22float2(hp[2]); dp[4] = f.x; dp[5] = f.y;
        f = __half22float2(hp[3]); dp[6] = f.x; dp[7] = f.y;
    }
    __syncthreads();

    int cg = tid & 15;
    int rg = tid >> 4;
    float acc1[4][4] = {{0.f}}, acc2[4][4] = {{0.f}};

    for (int k0 = 0; k0 < 64; k0 += 4) {
        float4 a[4], w1[4];
#pragma unroll
        for (int i = 0; i < 4; ++i) a[i] = *(const float4*)&At[4 * rg + i][k0];
#pragma unroll
        for (int j = 0; j < 4; ++j) w1[j] = *(const float4*)&Ws1[k0 + j][cg * 4];
#pragma unroll
        for (int i = 0; i < 4; ++i) {
            float av[4] = {a[i].x, a[i].y, a[i].z, a[i].w};
#pragma unroll
            for (int kk = 0; kk < 4; ++kk) {
                acc1[i][0] += av[kk] * w1[kk].x;
                acc1[i][1] += av[kk] * w1[kk].y;
                acc1[i][2] += av[kk] * w1[kk].z;
                acc1[i][3] += av[kk] * w1[kk].w;
            }
        }
        if (W2) {
            float4 w2[4];
#pragma unroll
            for (int j = 0; j < 4; ++j) w2[j] = *(const float4*)&Ws2[k0 + j][cg * 4];
#pragma unroll
            for (int i = 0; i < 4; ++i) {
                float av[4] = {a[i].x, a[i].y, a[i].z, a[i].w};
#pragma unroll
                for (int kk = 0; kk < 4; ++kk) {
                    acc2[i][0] += av[kk] * w2[kk].x;
                    acc2[i][1] += av[kk] * w2[kk].y;
                    acc2[i][2] += av[kk] * w2[kk].z;
                    acc2[i][3] += av[kk] * w2[kk].w;
                }
            }
        }
    }

    float4 bv = make_float4(0.f, 0.f, 0.f, 0.f);
    if (bias) bv = ((const float4*)bias)[cg];
#pragma unroll
    for (int i = 0; i < 4; ++i) {
        int gr = r0 + 4 * rg + i;
        if (gr < nrows) {
            float ox = acc1[i][0] + bv.x, oy = acc1[i][1] + bv.y;
            float oz = acc1[i][2] + bv.z, ow = acc1[i][3] + bv.w;
            if (do_relu) {
                ox = fmaxf(ox, 0.f); oy = fmaxf(oy, 0.f);
                oz = fmaxf(oz, 0.f); ow = fmaxf(ow, 0.f);
            }
            float2 oh;
            *(__half2*)&oh.x = __floats2half2_rn(ox, oy);
            *(__half2*)&oh.y = __floats2half2_rn(oz, ow);
            ((float2*)(out1 + (size_t)gr * D))[cg] = oh;
            if (out2) {
                float2 o2;
                *(__half2*)&o2.x = __floats2half2_rn(acc2[i][0], acc2[i][1]);
                *(__half2*)&o2.y = __floats2half2_rn(acc2[i][2], acc2[i][3]);
                ((float2*)(out2 + (size_t)gr * D))[cg] = o2;
            }
        }
    }
}

// ================= GCN: h1[v] = relu( sum embW[x[u]] ), masked-unrolled =================

__global__ __launch_bounds__(256) void gcn_kernel(const int* __restrict__ rowptr,
                                                  const int* __restrict__ col,
                                                  const float* __restrict__ embW,
                                                  __half* __restrict__ h1, int N, int V) {
    extern __shared__ float lembW[];
    int tid = threadIdx.x;
    for (int i = tid; i < V * D; i += 256) lembW[i] = embW[i];
    __syncthreads();
    int lane = tid & 63;
    int g2 = lane >> 5, lj = lane & 31;
    int wid = (blockIdx.x * 256 + tid) >> 6;
    int stride = (gridDim.x * 256) >> 6;
    for (int v = wid; v < N; v += stride) {
        int beg = rowptr[v], end = rowptr[v + 1];
        float ax = 0.f, ay = 0.f;
        for (int e0 = beg; e0 < end; e0 += 8) {
#pragma unroll
            for (int j = 0; j < 4; ++j) {
                int e = e0 + 2 * j + g2;
                float m = (e < end) ? 1.f : 0.f;
                int ec = (e < end) ? e : (end - 1);
                int xu = (col[ec] >> 16) & 0x7F;
                float2 f = *((const float2*)(lembW + xu * D) + lj);
                ax += m * f.x; ay += m * f.y;
            }
        }
        ax += __shfl_xor(ax, 32);
        ay += __shfl_xor(ay, 32);
        if (g2 == 0)
            ((__half2*)(h1 + (size_t)v * D))[lj] =
                __floats2half2_rn(fmaxf(ax, 0.f), fmaxf(ay, 0.f));
    }
}

// ================= SAGE epilogue: h2 = relu( agg(A)/deg + B ), masked-unrolled =================

__global__ __launch_bounds__(256) void sage_agg_kernel(const int* __restrict__ rowptr,
                                                       const int* __restrict__ col,
                                                       const __half* __restrict__ A,
                                                       const __half* __restrict__ B,
                                                       __half* __restrict__ h2, int N) {
    int tid = threadIdx.x;
    int lane = tid & 63;
    int grp = lane >> 4, li = lane & 15;
    int v = blockIdx.x * 4 + (tid >> 6);
    if (v >= N) return;
    int beg = rowptr[v], end = rowptr[v + 1];
    float a0 = 0.f, a1 = 0.f, a2 = 0.f, a3 = 0.f;
    for (int e0 = beg; e0 < end; e0 += 16) {
#pragma unroll
        for (int j = 0; j < 4; ++j) {
            int e = e0 + 4 * j + grp;
            float m = (e < end) ? 1.f : 0.f;
            int ec = (e < end) ? e : (end - 1);
            int u = col[ec] & 0xFFFF;
            float2 r = *((const float2*)(A + (size_t)u * D) + li);
            float2 f01 = __half22float2(*(const __half2*)&r.x);
            float2 f23 = __half22float2(*(const __half2*)&r.y);
            a0 += m * f01.x; a1 += m * f01.y; a2 += m * f23.x; a3 += m * f23.y;
        }
    }
    a0 += __shfl_xor(a0, 16); a0 += __shfl_xor(a0, 32);
    a1 += __shfl_xor(a1, 16); a1 += __shfl_xor(a1, 32);
    a2 += __shfl_xor(a2, 16); a2 += __shfl_xor(a2, 32);
    a3 += __shfl_xor(a3, 16); a3 += __shfl_xor(a3, 32);
    if (grp == 0) {
        float inv = 1.f / fmaxf((float)(end - beg), 1.f);
        float2 br = *((const float2*)(B + (size_t)v * D) + li);
        float2 b01 = __half22float2(*(const __half2*)&br.x);
        float2 b23 = __half22float2(*(const __half2*)&br.y);
        float2 oh;
        *(__half2*)&oh.x = __floats2half2_rn(fmaxf(a0 * inv + b01.x, 0.f),
                                             fmaxf(a1 * inv + b01.y, 0.f));
        *(__half2*)&oh.y = __floats2half2_rn(fmaxf(a2 * inv + b23.x, 0.f),
                                             fmaxf(a3 * inv + b23.y, 0.f));
        ((float2*)(h2 + (size_t)v * D))[li] = oh;
    }
}

// ================= GIN epilogue: t = relu( C + agg(C) + b1 ), masked-unrolled =================

__global__ __launch_bounds__(256) void gin_agg_kernel(const int* __restrict__ rowptr,
                                                      const int* __restrict__ col,
                                                      const __half* __restrict__ C,
                                                      const float* __restrict__ b1,
                                                      __half* __restrict__ t, int N) {
    int tid = threadIdx.x;
    int lane = tid & 63;
    int grp = lane >> 4, li = lane & 15;
    int v = blockIdx.x * 4 + (tid >> 6);
    if (v >= N) return;
    int beg = rowptr[v], end = rowptr[v + 1];
    float a0 = 0.f, a1 = 0.f, a2 = 0.f, a3 = 0.f;
    for (int e0 = beg; e0 < end; e0 += 16) {
#pragma unroll
        for (int j = 0; j < 4; ++j) {
            int e = e0 + 4 * j + grp;
            float m = (e < end) ? 1.f : 0.f;
            int ec = (e < end) ? e : (end - 1);
            int u = col[ec] & 0xFFFF;
            float2 r = *((const float2*)(C + (size_t)u * D) + li);
            float2 f01 = __half22float2(*(const __half2*)&r.x);
            float2 f23 = __half22float2(*(const __half2*)&r.y);
            a0 += m * f01.x; a1 += m * f01.y; a2 += m * f23.x; a3 += m * f23.y;
        }
    }
    a0 += __shfl_xor(a0, 16); a0 += __shfl_xor(a0, 32);
    a1 += __shfl_xor(a1, 16); a1 += __shfl_xor(a1, 32);
    a2 += __shfl_xor(a2, 16); a2 += __shfl_xor(a2, 32);
    a3 += __shfl_xor(a3, 16); a3 += __shfl_xor(a3, 32);
    if (grp == 0) {
        float2 rs = *((const float2*)(C + (size_t)v * D) + li);   // self term
        float2 s01 = __half22float2(*(const __half2*)&rs.x);
        float2 s23 = __half22float2(*(const __half2*)&rs.y);
        float4 bb = ((const float4*)b1)[li];
        float2 oh;
        *(__half2*)&oh.x = __floats2half2_rn(fmaxf(s01.x + a0 + bb.x, 0.f),
                                             fmaxf(s01.y + a1 + bb.y, 0.f));
        *(__half2*)&oh.y = __floats2half2_rn(fmaxf(s23.x + a2 + bb.z, 0.f),
                                             fmaxf(s23.y + a3 + bb.w, 0.f));
        ((float2*)(t + (size_t)v * D))[li] = oh;
    }
}

// ================= pooling: 16 waves per graph + LDS tree reduce (fp16 inputs) =================

__global__ __launch_bounds__(1024) void pool_final_kernel(
    const __half* __restrict__ h1, const __half* __restrict__ h2,
    const __half* __restrict__ h3,
    const int* __restrict__ batch, int N,
    const float* __restrict__ W1, const float* __restrict__ W2,
    const float* __restrict__ W3, float* __restrict__ out, int G) {
    __shared__ float r1[16][64];
    __shared__ float r2[16][64];
    __shared__ float r3[16][64];
    int g = blockIdx.x;
    int tid = threadIdx.x;
    int w = tid >> 6, lane = tid & 63;

    int lo = 0, hi = N;
    while (lo < hi) { int mid = (lo + hi) >> 1; if (batch[mid] < g) lo = mid + 1; else hi = mid; }
    int beg = lo;
    hi = N;
    while (lo < hi) { int mid = (lo + hi) >> 1; if (batch[mid] < g + 1) lo = mid + 1; else hi = mid; }
    int end = lo;

    float s1 = 0.f, s2 = 0.f, s3 = 0.f;
    for (int v = beg + w; v < end; v += 16) {
        size_t idx = (size_t)v * D + lane;
        s1 += __half2float(h1[idx]);
        s2 += __half2float(h2[idx]);
        s3 += __half2float(h3[idx]);
    }
    r1[w][lane] = s1; r2[w][lane] = s2; r3[w][lane] = s3;
    __syncthreads();
#pragma unroll
    for (int stride = 8; stride >= 1; stride >>= 1) {
        if (w < stride) {
            r1[w][lane] += r1[w + stride][lane];
            r2[w][lane] += r2[w + stride][lane];
            r3[w][lane] += r3[w + stride][lane];
        }
        __syncthreads();
    }
    if (w == 0) {
        float inv = 1.f / fmaxf((float)(end - beg), 1.f);
        float p1 = r1[0][lane] * inv, p2 = r2[0][lane] * inv, p3 = r3[0][lane] * inv;
        float acc = 0.f;
#pragma unroll
        for (int k = 0; k < D; ++k) {
            acc += __shfl(p1, k) * W1[k * D + lane]
                 + __shfl(p2, k) * W2[k * D + lane]
                 + __shfl(p3, k) * W3[k * D + lane];
        }
        out[(size_t)g * D + lane] = fmaxf(acc, 0.f);
    }
}

// ================= launch =================

static inline size_t align256(size_t x) { return (x + 255) & ~(size_t)255; }

extern "C" void kernel_launch(void* const* d_in, const int* in_sizes, int n_in,
                              void* d_out, int out_size, void* d_ws, size_t ws_size,
                              hipStream_t stream) {
    const int* x      = (const int*)d_in[0];
    const int* ei     = (const int*)d_in[1];
    const int* batch  = (const int*)d_in[2];
    const float* emb  = (const float*)d_in[3];
    const float* Wgcn = (const float*)d_in[4];
    const float* Wsl  = (const float*)d_in[5];
    const float* Wsr  = (const float*)d_in[6];
    const float* Wg1  = (const float*)d_in[7];
    const float* bg1  = (const float*)d_in[8];
    const float* Wg2  = (const float*)d_in[9];
    const float* bg2  = (const float*)d_in[10];
    const float* Wp1  = (const float*)d_in[11];
    const float* Wp2  = (const float*)d_in[12];
    const float* Wp3  = (const float*)d_in[13];
    float* out = (float*)d_out;

    const int N = in_sizes[0];
    const int E = in_sizes[1] / 2;
    const int V = in_sizes[3] / D;
    const int G = out_size / D;
    const int* src = ei;
    const int* dst = ei + E;
    const int NBUCK = (N + 255) >> 8;

    // workspace layout
    char* base = (char*)d_ws;
    size_t off = 0;
    float* embW    = (float*)(base + off); off = align256(off + (size_t)V * D * 4);
    int* bucketCount  = (int*)(base + off); off = align256(off + 260 * 4);   // +doneCtr after
    int* doneCtr      = bucketCount + 256;
    int* bucketBase   = (int*)(base + off); off = align256(off + 257 * 4);
    int* bucketCursor = (int*)(base + off); off = align256(off + 256 * 4);
    int* rowptr    = (int*)(base + off);   off = align256(off + (size_t)(N + 1) * 4);
    int* ebuf      = (int*)(base + off);   off = align256(off + (size_t)E * 4);
    int* col       = (int*)(base + off);   off = align256(off + (size_t)E * 4);
    __half* h1     = (__half*)(base + off); off = align256(off + (size_t)N * D * 2);
    __half* h2     = (__half*)(base + off); off = align256(off + (size_t)N * D * 2);
    __half* h3     = (__half*)(base + off); off = align256(off + (size_t)N * D * 2);
    __half* Ah     = (__half*)(base + off); off = align256(off + (size_t)N * D * 2);
    __half* B      = (__half*)(base + off); off = align256(off + (size_t)N * D * 2);
    (void)ws_size;

    __half* Ch = Ah;  // reuse: Ah dead after sage_agg
    __half* t  = B;   // reuse: B dead after sage_agg

    // zero bucketCount + doneCtr in one memset
    hipMemsetAsync(bucketCount, 0, 260 * 4, stream);

    // fused: bucket histogram + scan (last-block) + embW GEMM tiles
    int embTiles = (V + 63) / 64;
    count_scan_emb_kernel<<<256 + embTiles, 256, 0, stream>>>(
        dst, E, bucketCount, bucketBase, bucketCursor, doneCtr, emb, Wgcn, embW, V);

    scatter_kernel<<<(E + K3E - 1) / K3E, 256, 0, stream>>>(src, dst, x, bucketCursor, ebuf, E);
    csr_kernel<<<NBUCK, 256, 0, stream>>>(ebuf, bucketBase, rowptr, col, N, E);

    // GCN gather -> h1 (fp16)
    gcn_kernel<<<1024, 256, (size_t)V * D * 4, stream>>>(rowptr, col, embW, h1, N, V);

    // SAGE: Ah = fp16(h1@Wl), B = fp16(h1@Wr), then fused agg epilogue -> h2 (fp16)
    int gb = (N + 63) / 64;
    gemm64h_kernel<<<gb, 256, 0, stream>>>(h1, N, Wsl, Wsr, nullptr, 0, Ah, B);
    sage_agg_kernel<<<(N + 3) / 4, 256, 0, stream>>>(rowptr, col, Ah, B, h2, N);

    // GIN: Ch = fp16(h2@W1), t = relu(C + agg(C) + b1), h3 = fp16(relu(t@W2 + b2))
    gemm64h_kernel<<<gb, 256, 0, stream>>>(h2, N, Wg1, nullptr, nullptr, 0, Ch, nullptr);
    gin_agg_kernel<<<(N + 3) / 4, 256, 0, stream>>>(rowptr, col, Ch, bg1, t, N);
    gemm64h_kernel<<<gb, 256, 0, stream>>>(t, N, Wg2, nullptr, bg2, 1, h3, nullptr);

    // pooling (16 waves/graph, LDS reduce)
    pool_final_kernel<<<G, 1024, 0, stream>>>(h1, h2, h3, batch, N, Wp1, Wp2, Wp3, out, G);
}

// Round 9
// 260.051 us; speedup vs baseline: 1.0398x; 1.0398x over previous
//
#include <hip/hip_runtime.h>
#include <hip/hip_bf16.h>
#include <hip/hip_fp16.h>

#define D 64
#define K3E 4096

// Edge word packing (requires N <= 65536, V <= 128 — true for this problem):
//   bits [0:15]  = src node
//   bits [16:22] = x[src]   (vocab id)
//   bits [23:30] = dst & 255 (node index within its 256-node bucket)

// ================= fp32 GEMM (used once for embW, V=128 rows) =================

__global__ __launch_bounds__(256) void gemm64_kernel(
    const float* __restrict__ in, int nrows,
    const float* __restrict__ W1,
    float* __restrict__ out1)
{
    __shared__ float At[64][68];
    __shared__ float Ws1[64][64];
    int tid = threadIdx.x;
    {
        const float4* w1v = (const float4*)W1;
        float4* s1 = (float4*)&Ws1[0][0];
        for (int i = tid; i < 1024; i += 256) s1[i] = w1v[i];
    }
    int r0 = blockIdx.x * 64;
    for (int i = tid; i < 1024; i += 256) {
        int r = i >> 4, c4 = i & 15;
        int gr = r0 + r; if (gr >= nrows) gr = nrows - 1;
        float4 v = ((const float4*)(in + (size_t)gr * D))[c4];
        float* dp = &At[r][c4 * 4];
        dp[0] = v.x; dp[1] = v.y; dp[2] = v.z; dp[3] = v.w;
    }
    __syncthreads();

    int cg = tid & 15;
    int rg = tid >> 4;
    float acc1[4][4] = {{0.f}};

    for (int k0 = 0; k0 < 64; k0 += 4) {
        float4 a[4], w1[4];
#pragma unroll
        for (int i = 0; i < 4; ++i) a[i] = *(const float4*)&At[4 * rg + i][k0];
#pragma unroll
        for (int j = 0; j < 4; ++j) w1[j] = *(const float4*)&Ws1[k0 + j][cg * 4];
#pragma unroll
        for (int i = 0; i < 4; ++i) {
            float av[4] = {a[i].x, a[i].y, a[i].z, a[i].w};
#pragma unroll
            for (int kk = 0; kk < 4; ++kk) {
                acc1[i][0] += av[kk] * w1[kk].x;
                acc1[i][1] += av[kk] * w1[kk].y;
                acc1[i][2] += av[kk] * w1[kk].z;
                acc1[i][3] += av[kk] * w1[kk].w;
            }
        }
    }
#pragma unroll
    for (int i = 0; i < 4; ++i) {
        int gr = r0 + 4 * rg + i;
        if (gr < nrows) {
            float4 o;
            o.x = acc1[i][0]; o.y = acc1[i][1]; o.z = acc1[i][2]; o.w = acc1[i][3];
            ((float4*)(out1 + (size_t)gr * D))[cg] = o;
        }
    }
}

// ================= bucketed CSR build (separate low-VGPR kernels) =================

__global__ __launch_bounds__(256) void bucket_count_kernel(const int* __restrict__ dst, int E,
                                                           int* __restrict__ bucketCount) {
    __shared__ int hist[256];
    int t = threadIdx.x;
    hist[t] = 0;
    __syncthreads();
    for (int e = blockIdx.x * 256 + t; e < E; e += gridDim.x * 256)
        atomicAdd(&hist[dst[e] >> 8], 1);
    __syncthreads();
    int c = hist[t];
    if (c) atomicAdd(&bucketCount[t], c);
}

__global__ void bucket_scan_kernel(const int* __restrict__ bucketCount,
                                   int* __restrict__ bucketBase, int* __restrict__ bucketCursor) {
    __shared__ int lds[256];
    int t = threadIdx.x;
    int c = bucketCount[t];
    lds[t] = c;
    __syncthreads();
    for (int off = 1; off < 256; off <<= 1) {
        int v = (t >= off) ? lds[t - off] : 0;
        __syncthreads();
        lds[t] += v;
        __syncthreads();
    }
    int excl = lds[t] - c;
    bucketBase[t] = excl;
    bucketCursor[t] = excl;
    if (t == 255) bucketBase[256] = lds[t];
}

__global__ __launch_bounds__(256) void scatter_kernel(const int* __restrict__ src,
                                                      const int* __restrict__ dst,
                                                      const int* __restrict__ x,
                                                      int* __restrict__ bucketCursor,
                                                      int* __restrict__ ebuf, int E) {
    __shared__ int uu[K3E];
    __shared__ unsigned char bb[K3E];
    __shared__ int hist[256];
    __shared__ int resBase[256];
    int t = threadIdx.x;
    hist[t] = 0;
    __syncthreads();
    int e0 = blockIdx.x * K3E;
    int cnt = E - e0; if (cnt > K3E) cnt = K3E;
    for (int i = t; i < cnt; i += 256) {
        int e = e0 + i;
        int s = src[e];
        int d = dst[e];
        int xs = x[s];
        uu[i] = s | (xs << 16) | ((d & 255) << 23);
        int b = d >> 8;
        bb[i] = (unsigned char)b;
        atomicAdd(&hist[b], 1);
    }
    __syncthreads();
    int c = hist[t];
    if (c) resBase[t] = atomicAdd(&bucketCursor[t], c);
    __syncthreads();
    hist[t] = 0;
    __syncthreads();
    for (int i = t; i < cnt; i += 256) {
        int b = bb[i];
        int r = atomicAdd(&hist[b], 1);
        ebuf[resBase[b] + r] = uu[i];
    }
}

__global__ __launch_bounds__(256) void csr_kernel(const int* __restrict__ ebuf,
                                                  const int* __restrict__ bucketBase,
                                                  int* __restrict__ rowptr, int* __restrict__ col,
                                                  int N, int E) {
    __shared__ int hist[256];
    __shared__ int sc[256];
    int b = blockIdx.x, t = threadIdx.x;
    int base = bucketBase[b], endb = bucketBase[b + 1];
    int m = endb - base;
    hist[t] = 0;
    __syncthreads();
    for (int i = t; i < m; i += 256)
        atomicAdd(&hist[(ebuf[base + i] >> 23) & 255], 1);
    __syncthreads();
    int v = hist[t];
    sc[t] = v;
    __syncthreads();
    for (int off = 1; off < 256; off <<= 1) {
        int w = (t >= off) ? sc[t - off] : 0;
        __syncthreads();
        sc[t] += w;
        __syncthreads();
    }
    int excl = sc[t] - v;
    int node = (b << 8) + t;
    if (node < N) rowptr[node] = base + excl;
    if (b == gridDim.x - 1 && t == 0) rowptr[N] = E;
    __syncthreads();
    hist[t] = excl;   // running local cursor
    __syncthreads();
    for (int i = t; i < m; i += 256) {
        int u = ebuf[base + i];
        int dl = (u >> 23) & 255;
        int r = atomicAdd(&hist[dl], 1);
        col[base + r] = u;
    }
}

// ===== fp16-in / fp16-out GEMM (fp32 LDS + fp32 accumulate), optional dual output =====

__global__ __launch_bounds__(256) void gemm64h_kernel(
    const __half* __restrict__ in, int nrows,
    const float* __restrict__ W1, const float* __restrict__ W2,
    const float* __restrict__ bias, int do_relu,
    __half* __restrict__ out1, __half* __restrict__ out2)
{
    __shared__ float At[64][68];
    __shared__ float Ws1[64][64];
    __shared__ float Ws2[64][64];
    int tid = threadIdx.x;
    {
        const float4* w1v = (const float4*)W1;
        float4* s1 = (float4*)&Ws1[0][0];
        for (int i = tid; i < 1024; i += 256) s1[i] = w1v[i];
        if (W2) {
            const float4* w2v = (const float4*)W2;
            float4* s2 = (float4*)&Ws2[0][0];
            for (int i = tid; i < 1024; i += 256) s2[i] = w2v[i];
        }
    }
    int r0 = blockIdx.x * 64;
    for (int i = tid; i < 512; i += 256) {
        int r = i >> 3, c8 = i & 7;
        int gr = r0 + r; if (gr >= nrows) gr = nrows - 1;
        float4 hv = ((const float4*)(in + (size_t)gr * D))[c8];
        const __half2* hp = (const __half2*)&hv;
        float* dp = &At[r][c8 * 8];
        float2 f;
        f = __half22float2(hp[0]); dp[0] = f.x; dp[1] = f.y;
        f = __half22float2(hp[1]); dp[2] = f.x; dp[3] = f.y;
        f = __half22float2(hp[2]); dp[4] = f.x; dp[5] = f.y;
        f = __half22float2(hp[3]); dp[6] = f.x; dp[7] = f.y;
    }
    __syncthreads();

    int cg = tid & 15;
    int rg = tid >> 4;
    float acc1[4][4] = {{0.f}}, acc2[4][4] = {{0.f}};

    for (int k0 = 0; k0 < 64; k0 += 4) {
        float4 a[4], w1[4];
#pragma unroll
        for (int i = 0; i < 4; ++i) a[i] = *(const float4*)&At[4 * rg + i][k0];
#pragma unroll
        for (int j = 0; j < 4; ++j) w1[j] = *(const float4*)&Ws1[k0 + j][cg * 4];
#pragma unroll
        for (int i = 0; i < 4; ++i) {
            float av[4] = {a[i].x, a[i].y, a[i].z, a[i].w};
#pragma unroll
            for (int kk = 0; kk < 4; ++kk) {
                acc1[i][0] += av[kk] * w1[kk].x;
                acc1[i][1] += av[kk] * w1[kk].y;
                acc1[i][2] += av[kk] * w1[kk].z;
                acc1[i][3] += av[kk] * w1[kk].w;
            }
        }
        if (W2) {
            float4 w2[4];
#pragma unroll
            for (int j = 0; j < 4; ++j) w2[j] = *(const float4*)&Ws2[k0 + j][cg * 4];
#pragma unroll
            for (int i = 0; i < 4; ++i) {
                float av[4] = {a[i].x, a[i].y, a[i].z, a[i].w};
#pragma unroll
                for (int kk = 0; kk < 4; ++kk) {
                    acc2[i][0] += av[kk] * w2[kk].x;
                    acc2[i][1] += av[kk] * w2[kk].y;
                    acc2[i][2] += av[kk] * w2[kk].z;
                    acc2[i][3] += av[kk] * w2[kk].w;
                }
            }
        }
    }

    float4 bv = make_float4(0.f, 0.f, 0.f, 0.f);
    if (bias) bv = ((const float4*)bias)[cg];
#pragma unroll
    for (int i = 0; i < 4; ++i) {
        int gr = r0 + 4 * rg + i;
        if (gr < nrows) {
            float ox = acc1[i][0] + bv.x, oy = acc1[i][1] + bv.y;
            float oz = acc1[i][2] + bv.z, ow = acc1[i][3] + bv.w;
            if (do_relu) {
                ox = fmaxf(ox, 0.f); oy = fmaxf(oy, 0.f);
                oz = fmaxf(oz, 0.f); ow = fmaxf(ow, 0.f);
            }
            float2 oh;
            *(__half2*)&oh.x = __floats2half2_rn(ox, oy);
            *(__half2*)&oh.y = __floats2half2_rn(oz, ow);
            ((float2*)(out1 + (size_t)gr * D))[cg] = oh;
            if (out2) {
                float2 o2;
                *(__half2*)&o2.x = __floats2half2_rn(acc2[i][0], acc2[i][1]);
                *(__half2*)&o2.y = __floats2half2_rn(acc2[i][2], acc2[i][3]);
                ((float2*)(out2 + (size_t)gr * D))[cg] = o2;
            }
        }
    }
}

// ================= GCN: h1[v] = relu( sum embW[x[u]] ), masked-unrolled =================

__global__ __launch_bounds__(256) void gcn_kernel(const int* __restrict__ rowptr,
                                                  const int* __restrict__ col,
                                                  const float* __restrict__ embW,
                                                  __half* __restrict__ h1, int N, int V) {
    extern __shared__ float lembW[];
    int tid = threadIdx.x;
    for (int i = tid; i < V * D; i += 256) lembW[i] = embW[i];
    __syncthreads();
    int lane = tid & 63;
    int g2 = lane >> 5, lj = lane & 31;
    int wid = (blockIdx.x * 256 + tid) >> 6;
    int stride = (gridDim.x * 256) >> 6;
    for (int v = wid; v < N; v += stride) {
        int beg = rowptr[v], end = rowptr[v + 1];
        float ax = 0.f, ay = 0.f;
        for (int e0 = beg; e0 < end; e0 += 8) {
#pragma unroll
            for (int j = 0; j < 4; ++j) {
                int e = e0 + 2 * j + g2;
                float m = (e < end) ? 1.f : 0.f;
                int ec = (e < end) ? e : (end - 1);
                int xu = (col[ec] >> 16) & 0x7F;
                float2 f = *((const float2*)(lembW + xu * D) + lj);
                ax += m * f.x; ay += m * f.y;
            }
        }
        ax += __shfl_xor(ax, 32);
        ay += __shfl_xor(ay, 32);
        if (g2 == 0)
            ((__half2*)(h1 + (size_t)v * D))[lj] =
                __floats2half2_rn(fmaxf(ax, 0.f), fmaxf(ay, 0.f));
    }
}

// ================= SAGE epilogue: h2 = relu( agg(A)/deg + B ), masked-unrolled =================

__global__ __launch_bounds__(256) void sage_agg_kernel(const int* __restrict__ rowptr,
                                                       const int* __restrict__ col,
                                                       const __half* __restrict__ A,
                                                       const __half* __restrict__ B,
                                                       __half* __restrict__ h2, int N) {
    int tid = threadIdx.x;
    int lane = tid & 63;
    int grp = lane >> 4, li = lane & 15;
    int v = blockIdx.x * 4 + (tid >> 6);
    if (v >= N) return;
    int beg = rowptr[v], end = rowptr[v + 1];
    float a0 = 0.f, a1 = 0.f, a2 = 0.f, a3 = 0.f;
    for (int e0 = beg; e0 < end; e0 += 16) {
#pragma unroll
        for (int j = 0; j < 4; ++j) {
            int e = e0 + 4 * j + grp;
            float m = (e < end) ? 1.f : 0.f;
            int ec = (e < end) ? e : (end - 1);
            int u = col[ec] & 0xFFFF;
            float2 r = *((const float2*)(A + (size_t)u * D) + li);
            float2 f01 = __half22float2(*(const __half2*)&r.x);
            float2 f23 = __half22float2(*(const __half2*)&r.y);
            a0 += m * f01.x; a1 += m * f01.y; a2 += m * f23.x; a3 += m * f23.y;
        }
    }
    a0 += __shfl_xor(a0, 16); a0 += __shfl_xor(a0, 32);
    a1 += __shfl_xor(a1, 16); a1 += __shfl_xor(a1, 32);
    a2 += __shfl_xor(a2, 16); a2 += __shfl_xor(a2, 32);
    a3 += __shfl_xor(a3, 16); a3 += __shfl_xor(a3, 32);
    if (grp == 0) {
        float inv = 1.f / fmaxf((float)(end - beg), 1.f);
        float2 br = *((const float2*)(B + (size_t)v * D) + li);
        float2 b01 = __half22float2(*(const __half2*)&br.x);
        float2 b23 = __half22float2(*(const __half2*)&br.y);
        float2 oh;
        *(__half2*)&oh.x = __floats2half2_rn(fmaxf(a0 * inv + b01.x, 0.f),
                                             fmaxf(a1 * inv + b01.y, 0.f));
        *(__half2*)&oh.y = __floats2half2_rn(fmaxf(a2 * inv + b23.x, 0.f),
                                             fmaxf(a3 * inv + b23.y, 0.f));
        ((float2*)(h2 + (size_t)v * D))[li] = oh;
    }
}

// ================= GIN epilogue: t = relu( C + agg(C) + b1 ), masked-unrolled =================

__global__ __launch_bounds__(256) void gin_agg_kernel(const int* __restrict__ rowptr,
                                                      const int* __restrict__ col,
                                                      const __half* __restrict__ C,
                                                      const float* __restrict__ b1,
                                                      __half* __restrict__ t, int N) {
    int tid = threadIdx.x;
    int lane = tid & 63;
    int grp = lane >> 4, li = lane & 15;
    int v = blockIdx.x * 4 + (tid >> 6);
    if (v >= N) return;
    int beg = rowptr[v], end = rowptr[v + 1];
    float a0 = 0.f, a1 = 0.f, a2 = 0.f, a3 = 0.f;
    for (int e0 = beg; e0 < end; e0 += 16) {
#pragma unroll
        for (int j = 0; j < 4; ++j) {
            int e = e0 + 4 * j + grp;
            float m = (e < end) ? 1.f : 0.f;
            int ec = (e < end) ? e : (end - 1);
            int u = col[ec] & 0xFFFF;
            float2 r = *((const float2*)(C + (size_t)u * D) + li);
            float2 f01 = __half22float2(*(const __half2*)&r.x);
            float2 f23 = __half22float2(*(const __half2*)&r.y);
            a0 += m * f01.x; a1 += m * f01.y; a2 += m * f23.x; a3 += m * f23.y;
        }
    }
    a0 += __shfl_xor(a0, 16); a0 += __shfl_xor(a0, 32);
    a1 += __shfl_xor(a1, 16); a1 += __shfl_xor(a1, 32);
    a2 += __shfl_xor(a2, 16); a2 += __shfl_xor(a2, 32);
    a3 += __shfl_xor(a3, 16); a3 += __shfl_xor(a3, 32);
    if (grp == 0) {
        float2 rs = *((const float2*)(C + (size_t)v * D) + li);   // self term
        float2 s01 = __half22float2(*(const __half2*)&rs.x);
        float2 s23 = __half22float2(*(const __half2*)&rs.y);
        float4 bb = ((const float4*)b1)[li];
        float2 oh;
        *(__half2*)&oh.x = __floats2half2_rn(fmaxf(s01.x + a0 + bb.x, 0.f),
                                             fmaxf(s01.y + a1 + bb.y, 0.f));
        *(__half2*)&oh.y = __floats2half2_rn(fmaxf(s23.x + a2 + bb.z, 0.f),
                                             fmaxf(s23.y + a3 + bb.w, 0.f));
        ((float2*)(t + (size_t)v * D))[li] = oh;
    }
}

// ================= pooling: 16 waves per graph + LDS tree reduce (fp16 inputs) =================

__global__ __launch_bounds__(1024) void pool_final_kernel(
    const __half* __restrict__ h1, const __half* __restrict__ h2,
    const __half* __restrict__ h3,
    const int* __restrict__ batch, int N,
    const float* __restrict__ W1, const float* __restrict__ W2,
    const float* __restrict__ W3, float* __restrict__ out, int G) {
    __shared__ float r1[16][64];
    __shared__ float r2[16][64];
    __shared__ float r3[16][64];
    int g = blockIdx.x;
    int tid = threadIdx.x;
    int w = tid >> 6, lane = tid & 63;

    int lo = 0, hi = N;
    while (lo < hi) { int mid = (lo + hi) >> 1; if (batch[mid] < g) lo = mid + 1; else hi = mid; }
    int beg = lo;
    hi = N;
    while (lo < hi) { int mid = (lo + hi) >> 1; if (batch[mid] < g + 1) lo = mid + 1; else hi = mid; }
    int end = lo;

    float s1 = 0.f, s2 = 0.f, s3 = 0.f;
    for (int v = beg + w; v < end; v += 16) {
        size_t idx = (size_t)v * D + lane;
        s1 += __half2float(h1[idx]);
        s2 += __half2float(h2[idx]);
        s3 += __half2float(h3[idx]);
    }
    r1[w][lane] = s1; r2[w][lane] = s2; r3[w][lane] = s3;
    __syncthreads();
#pragma unroll
    for (int stride = 8; stride >= 1; stride >>= 1) {
        if (w < stride) {
            r1[w][lane] += r1[w + stride][lane];
            r2[w][lane] += r2[w + stride][lane];
            r3[w][lane] += r3[w + stride][lane];
        }
        __syncthreads();
    }
    if (w == 0) {
        float inv = 1.f / fmaxf((float)(end - beg), 1.f);
        float p1 = r1[0][lane] * inv, p2 = r2[0][lane] * inv, p3 = r3[0][lane] * inv;
        float acc = 0.f;
#pragma unroll
        for (int k = 0; k < D; ++k) {
            acc += __shfl(p1, k) * W1[k * D + lane]
                 + __shfl(p2, k) * W2[k * D + lane]
                 + __shfl(p3, k) * W3[k * D + lane];
        }
        out[(size_t)g * D + lane] = fmaxf(acc, 0.f);
    }
}

// ================= launch =================

static inline size_t align256(size_t x) { return (x + 255) & ~(size_t)255; }

extern "C" void kernel_launch(void* const* d_in, const int* in_sizes, int n_in,
                              void* d_out, int out_size, void* d_ws, size_t ws_size,
                              hipStream_t stream) {
    const int* x      = (const int*)d_in[0];
    const int* ei     = (const int*)d_in[1];
    const int* batch  = (const int*)d_in[2];
    const float* emb  = (const float*)d_in[3];
    const float* Wgcn = (const float*)d_in[4];
    const float* Wsl  = (const float*)d_in[5];
    const float* Wsr  = (const float*)d_in[6];
    const float* Wg1  = (const float*)d_in[7];
    const float* bg1  = (const float*)d_in[8];
    const float* Wg2  = (const float*)d_in[9];
    const float* bg2  = (const float*)d_in[10];
    const float* Wp1  = (const float*)d_in[11];
    const float* Wp2  = (const float*)d_in[12];
    const float* Wp3  = (const float*)d_in[13];
    float* out = (float*)d_out;

    const int N = in_sizes[0];
    const int E = in_sizes[1] / 2;
    const int V = in_sizes[3] / D;
    const int G = out_size / D;
    const int* src = ei;
    const int* dst = ei + E;
    const int NBUCK = (N + 255) >> 8;

    // workspace layout
    char* base = (char*)d_ws;
    size_t off = 0;
    float* embW    = (float*)(base + off); off = align256(off + (size_t)V * D * 4);
    int* bucketCount  = (int*)(base + off); off = align256(off + 256 * 4);
    int* bucketBase   = (int*)(base + off); off = align256(off + 257 * 4);
    int* bucketCursor = (int*)(base + off); off = align256(off + 256 * 4);
    int* rowptr    = (int*)(base + off);   off = align256(off + (size_t)(N + 1) * 4);
    int* ebuf      = (int*)(base + off);   off = align256(off + (size_t)E * 4);
    int* col       = (int*)(base + off);   off = align256(off + (size_t)E * 4);
    __half* h1     = (__half*)(base + off); off = align256(off + (size_t)N * D * 2);
    __half* h2     = (__half*)(base + off); off = align256(off + (size_t)N * D * 2);
    __half* h3     = (__half*)(base + off); off = align256(off + (size_t)N * D * 2);
    __half* Ah     = (__half*)(base + off); off = align256(off + (size_t)N * D * 2);
    __half* B      = (__half*)(base + off); off = align256(off + (size_t)N * D * 2);
    (void)ws_size;

    __half* Ch = Ah;  // reuse: Ah dead after sage_agg
    __half* t  = B;   // reuse: B dead after sage_agg

    hipMemsetAsync(bucketCount, 0, 256 * 4, stream);

    // embW = emb @ Wgcn (fp32, tiny, separate low-pressure kernel)
    gemm64_kernel<<<(V + 63) / 64, 256, 0, stream>>>(emb, V, Wgcn, embW);

    // CSR build (bucketed, round-7 structure)
    bucket_count_kernel<<<256, 256, 0, stream>>>(dst, E, bucketCount);
    bucket_scan_kernel<<<1, 256, 0, stream>>>(bucketCount, bucketBase, bucketCursor);
    scatter_kernel<<<(E + K3E - 1) / K3E, 256, 0, stream>>>(src, dst, x, bucketCursor, ebuf, E);
    csr_kernel<<<NBUCK, 256, 0, stream>>>(ebuf, bucketBase, rowptr, col, N, E);

    // GCN gather -> h1 (fp16)
    gcn_kernel<<<1024, 256, (size_t)V * D * 4, stream>>>(rowptr, col, embW, h1, N, V);

    // SAGE: Ah = fp16(h1@Wl), B = fp16(h1@Wr), then fused agg epilogue -> h2 (fp16)
    int gb = (N + 63) / 64;
    gemm64h_kernel<<<gb, 256, 0, stream>>>(h1, N, Wsl, Wsr, nullptr, 0, Ah, B);
    sage_agg_kernel<<<(N + 3) / 4, 256, 0, stream>>>(rowptr, col, Ah, B, h2, N);

    // GIN: Ch = fp16(h2@W1), t = relu(C + agg(C) + b1), h3 = fp16(relu(t@W2 + b2))
    gemm64h_kernel<<<gb, 256, 0, stream>>>(h2, N, Wg1, nullptr, nullptr, 0, Ch, nullptr);
    gin_agg_kernel<<<(N + 3) / 4, 256, 0, stream>>>(rowptr, col, Ch, bg1, t, N);
    gemm64h_kernel<<<gb, 256, 0, stream>>>(t, N, Wg2, nullptr, bg2, 1, h3, nullptr);

    // pooling (16 waves/graph, LDS reduce)
    pool_final_kernel<<<G, 1024, 0, stream>>>(h1, h2, h3, batch, N, Wp1, Wp2, Wp3, out, G);
}

// Round 10
// 258.256 us; speedup vs baseline: 1.0471x; 1.0070x over previous
//
#include <hip/hip_runtime.h>
#include <hip/hip_bf16.h>
#include <hip/hip_fp16.h>

#define D 64
#define K3E 4096
#define ECAP 6144   // max edges per 256-node bucket held in LDS (mean 4082, sigma 64 -> 32 sigma)

// Edge word packing (requires N <= 65536, V <= 128 — true for this problem):
//   bits [0:15]  = src node
//   bits [16:22] = x[src]   (vocab id)
//   bits [23:30] = dst & 255 (node index within its 256-node bucket)

// ================= fp32 GEMM (used once for embW, V=128 rows) =================

__global__ __launch_bounds__(256) void gemm64_kernel(
    const float* __restrict__ in, int nrows,
    const float* __restrict__ W1,
    float* __restrict__ out1)
{
    __shared__ float At[64][68];
    __shared__ float Ws1[64][64];
    int tid = threadIdx.x;
    {
        const float4* w1v = (const float4*)W1;
        float4* s1 = (float4*)&Ws1[0][0];
        for (int i = tid; i < 1024; i += 256) s1[i] = w1v[i];
    }
    int r0 = blockIdx.x * 64;
    for (int i = tid; i < 1024; i += 256) {
        int r = i >> 4, c4 = i & 15;
        int gr = r0 + r; if (gr >= nrows) gr = nrows - 1;
        float4 v = ((const float4*)(in + (size_t)gr * D))[c4];
        float* dp = &At[r][c4 * 4];
        dp[0] = v.x; dp[1] = v.y; dp[2] = v.z; dp[3] = v.w;
    }
    __syncthreads();

    int cg = tid & 15;
    int rg = tid >> 4;
    float acc1[4][4] = {{0.f}};

    for (int k0 = 0; k0 < 64; k0 += 4) {
        float4 a[4], w1[4];
#pragma unroll
        for (int i = 0; i < 4; ++i) a[i] = *(const float4*)&At[4 * rg + i][k0];
#pragma unroll
        for (int j = 0; j < 4; ++j) w1[j] = *(const float4*)&Ws1[k0 + j][cg * 4];
#pragma unroll
        for (int i = 0; i < 4; ++i) {
            float av[4] = {a[i].x, a[i].y, a[i].z, a[i].w};
#pragma unroll
            for (int kk = 0; kk < 4; ++kk) {
                acc1[i][0] += av[kk] * w1[kk].x;
                acc1[i][1] += av[kk] * w1[kk].y;
                acc1[i][2] += av[kk] * w1[kk].z;
                acc1[i][3] += av[kk] * w1[kk].w;
            }
        }
    }
#pragma unroll
    for (int i = 0; i < 4; ++i) {
        int gr = r0 + 4 * rg + i;
        if (gr < nrows) {
            float4 o;
            o.x = acc1[i][0]; o.y = acc1[i][1]; o.z = acc1[i][2]; o.w = acc1[i][3];
            ((float4*)(out1 + (size_t)gr * D))[cg] = o;
        }
    }
}

// ================= bucketed CSR build (low-VGPR front-end) =================

__global__ __launch_bounds__(256) void bucket_count_kernel(const int* __restrict__ dst, int E,
                                                           int* __restrict__ bucketCount) {
    __shared__ int hist[256];
    int t = threadIdx.x;
    hist[t] = 0;
    __syncthreads();
    for (int e = blockIdx.x * 256 + t; e < E; e += gridDim.x * 256)
        atomicAdd(&hist[dst[e] >> 8], 1);
    __syncthreads();
    int c = hist[t];
    if (c) atomicAdd(&bucketCount[t], c);
}

__global__ void bucket_scan_kernel(const int* __restrict__ bucketCount,
                                   int* __restrict__ bucketBase, int* __restrict__ bucketCursor) {
    __shared__ int lds[256];
    int t = threadIdx.x;
    int c = bucketCount[t];
    lds[t] = c;
    __syncthreads();
    for (int off = 1; off < 256; off <<= 1) {
        int v = (t >= off) ? lds[t - off] : 0;
        __syncthreads();
        lds[t] += v;
        __syncthreads();
    }
    int excl = lds[t] - c;
    bucketBase[t] = excl;
    bucketCursor[t] = excl;
    if (t == 255) bucketBase[256] = lds[t];
}

__global__ __launch_bounds__(256) void scatter_kernel(const int* __restrict__ src,
                                                      const int* __restrict__ dst,
                                                      const int* __restrict__ x,
                                                      int* __restrict__ bucketCursor,
                                                      int* __restrict__ ebuf, int E) {
    __shared__ int uu[K3E];
    __shared__ unsigned char bb[K3E];
    __shared__ int hist[256];
    __shared__ int resBase[256];
    int t = threadIdx.x;
    hist[t] = 0;
    __syncthreads();
    int e0 = blockIdx.x * K3E;
    int cnt = E - e0; if (cnt > K3E) cnt = K3E;
    for (int i = t; i < cnt; i += 256) {
        int e = e0 + i;
        int s = src[e];
        int d = dst[e];
        int xs = x[s];
        uu[i] = s | (xs << 16) | ((d & 255) << 23);
        int b = d >> 8;
        bb[i] = (unsigned char)b;
        atomicAdd(&hist[b], 1);
    }
    __syncthreads();
    int c = hist[t];
    if (c) resBase[t] = atomicAdd(&bucketCursor[t], c);
    __syncthreads();
    hist[t] = 0;
    __syncthreads();
    for (int i = t; i < cnt; i += 256) {
        int b = bb[i];
        int r = atomicAdd(&hist[b], 1);
        ebuf[resBase[b] + r] = uu[i];
    }
}

// ===== fused: per-bucket exact CSR + GCN gather (h1) =====
// 1024 threads = 16 waves. Phase A: hist + scan + placement (same arithmetic
// as the old csr_kernel). Phase B: each wave computes h1 for 16 of the
// bucket's 256 nodes, reading placed edges from just-written col (same-CU L2,
// visible after __syncthreads) and embW from LDS. Low VGPR both phases.

__global__ __launch_bounds__(1024) void csr_gcn_kernel(
    const int* __restrict__ ebuf, const int* __restrict__ bucketBase,
    const float* __restrict__ embW,
    int* __restrict__ rowptr, int* __restrict__ col,
    __half* __restrict__ h1, int N, int E, int V)
{
    __shared__ int   eLds[ECAP];       // 24 KB
    __shared__ float lembW[128 * D];   // 32 KB (V<=128)
    __shared__ int   hist[256];        // 1 KB
    __shared__ int   sc[256];          // 1 KB
    __shared__ int   begS[256];        // 1 KB
    int b = blockIdx.x, t = threadIdx.x;
    int base = bucketBase[b], endb = bucketBase[b + 1];
    int m = endb - base;
    bool useLds = (m <= ECAP);

    // stage embW (all 16 waves)
    for (int i = t; i < V * D; i += 1024) lembW[i] = embW[i];
    if (t < 256) hist[t] = 0;
    __syncthreads();

    // histogram (+ LDS edge cache)
    for (int i = t; i < m; i += 1024) {
        int u = ebuf[base + i];
        if (useLds) eLds[i] = u;
        atomicAdd(&hist[(u >> 23) & 255], 1);
    }
    __syncthreads();

    // inclusive scan over 256 node counts (first 256 threads; all hit barriers)
    int v = (t < 256) ? hist[t] : 0;
    if (t < 256) sc[t] = v;
    __syncthreads();
    for (int off = 1; off < 256; off <<= 1) {
        int w = (t >= off && t < 256) ? sc[t - off] : 0;
        __syncthreads();
        if (t < 256) sc[t] += w;
        __syncthreads();
    }
    if (t < 256) {
        int excl = sc[t] - v;
        begS[t] = excl;
        int node = (b << 8) + t;
        if (node < N) rowptr[node] = base + excl;
        hist[t] = excl;   // running local cursor
    }
    if (b == gridDim.x - 1 && t == 0) rowptr[N] = E;
    __syncthreads();

    // placement
    for (int i = t; i < m; i += 1024) {
        int u = useLds ? eLds[i] : ebuf[base + i];
        int dl = (u >> 23) & 255;
        int r = atomicAdd(&hist[dl], 1);
        col[base + r] = u;
    }
    __syncthreads();

    // phase B: GCN gather for this bucket's nodes (wave w -> nodes w*16..w*16+15)
    int w = t >> 6, lane = t & 63;
    int g2 = lane >> 5, lj = lane & 31;
    for (int i = 0; i < 16; ++i) {
        int nt = w * 16 + i;
        int node = (b << 8) + nt;
        if (node >= N) break;
        int beg = base + begS[nt], end = base + sc[nt];
        float ax = 0.f, ay = 0.f;
        for (int e0 = beg; e0 < end; e0 += 8) {
#pragma unroll
            for (int j = 0; j < 4; ++j) {
                int e = e0 + 2 * j + g2;
                float mm = (e < end) ? 1.f : 0.f;
                int ec = (e < end) ? e : (end - 1);
                int xu = (col[ec] >> 16) & 0x7F;
                float2 f = *((const float2*)(lembW + xu * D) + lj);
                ax += mm * f.x; ay += mm * f.y;
            }
        }
        ax += __shfl_xor(ax, 32);
        ay += __shfl_xor(ay, 32);
        if (g2 == 0)
            ((__half2*)(h1 + (size_t)node * D))[lj] =
                __floats2half2_rn(fmaxf(ax, 0.f), fmaxf(ay, 0.f));
    }
}

// ===== fp16-in / fp16-out GEMM (fp32 LDS + fp32 accumulate), optional dual output =====

__global__ __launch_bounds__(256) void gemm64h_kernel(
    const __half* __restrict__ in, int nrows,
    const float* __restrict__ W1, const float* __restrict__ W2,
    const float* __restrict__ bias, int do_relu,
    __half* __restrict__ out1, __half* __restrict__ out2)
{
    __shared__ float At[64][68];
    __shared__ float Ws1[64][64];
    __shared__ float Ws2[64][64];
    int tid = threadIdx.x;
    {
        const float4* w1v = (const float4*)W1;
        float4* s1 = (float4*)&Ws1[0][0];
        for (int i = tid; i < 1024; i += 256) s1[i] = w1v[i];
        if (W2) {
            const float4* w2v = (const float4*)W2;
            float4* s2 = (float4*)&Ws2[0][0];
            for (int i = tid; i < 1024; i += 256) s2[i] = w2v[i];
        }
    }
    int r0 = blockIdx.x * 64;
    for (int i = tid; i < 512; i += 256) {
        int r = i >> 3, c8 = i & 7;
        int gr = r0 + r; if (gr >= nrows) gr = nrows - 1;
        float4 hv = ((const float4*)(in + (size_t)gr * D))[c8];
        const __half2* hp = (const __half2*)&hv;
        float* dp = &At[r][c8 * 8];
        float2 f;
        f = __half22float2(hp[0]); dp[0] = f.x; dp[1] = f.y;
        f = __half22float2(hp[1]); dp[2] = f.x; dp[3] = f.y;
        f = __half22float2(hp[2]); dp[4] = f.x; dp[5] = f.y;
        f = __half22float2(hp[3]); dp[6] = f.x; dp[7] = f.y;
    }
    __syncthreads();

    int cg = tid & 15;
    int rg = tid >> 4;
    float acc1[4][4] = {{0.f}}, acc2[4][4] = {{0.f}};

    for (int k0 = 0; k0 < 64; k0 += 4) {
        float4 a[4], w1[4];
#pragma unroll
        for (int i = 0; i < 4; ++i) a[i] = *(const float4*)&At[4 * rg + i][k0];
#pragma unroll
        for (int j = 0; j < 4; ++j) w1[j] = *(const float4*)&Ws1[k0 + j][cg * 4];
#pragma unroll
        for (int i = 0; i < 4; ++i) {
            float av[4] = {a[i].x, a[i].y, a[i].z, a[i].w};
#pragma unroll
            for (int kk = 0; kk < 4; ++kk) {
                acc1[i][0] += av[kk] * w1[kk].x;
                acc1[i][1] += av[kk] * w1[kk].y;
                acc1[i][2] += av[kk] * w1[kk].z;
                acc1[i][3] += av[kk] * w1[kk].w;
            }
        }
        if (W2) {
            float4 w2[4];
#pragma unroll
            for (int j = 0; j < 4; ++j) w2[j] = *(const float4*)&Ws2[k0 + j][cg * 4];
#pragma unroll
            for (int i = 0; i < 4; ++i) {
                float av[4] = {a[i].x, a[i].y, a[i].z, a[i].w};
#pragma unroll
                for (int kk = 0; kk < 4; ++kk) {
                    acc2[i][0] += av[kk] * w2[kk].x;
                    acc2[i][1] += av[kk] * w2[kk].y;
                    acc2[i][2] += av[kk] * w2[kk].z;
                    acc2[i][3] += av[kk] * w2[kk].w;
                }
            }
        }
    }

    float4 bv = make_float4(0.f, 0.f, 0.f, 0.f);
    if (bias) bv = ((const float4*)bias)[cg];
#pragma unroll
    for (int i = 0; i < 4; ++i) {
        int gr = r0 + 4 * rg + i;
        if (gr < nrows) {
            float ox = acc1[i][0] + bv.x, oy = acc1[i][1] + bv.y;
            float oz = acc1[i][2] + bv.z, ow = acc1[i][3] + bv.w;
            if (do_relu) {
                ox = fmaxf(ox, 0.f); oy = fmaxf(oy, 0.f);
                oz = fmaxf(oz, 0.f); ow = fmaxf(ow, 0.f);
            }
            float2 oh;
            *(__half2*)&oh.x = __floats2half2_rn(ox, oy);
            *(__half2*)&oh.y = __floats2half2_rn(oz, ow);
            ((float2*)(out1 + (size_t)gr * D))[cg] = oh;
            if (out2) {
                float2 o2;
                *(__half2*)&o2.x = __floats2half2_rn(acc2[i][0], acc2[i][1]);
                *(__half2*)&o2.y = __floats2half2_rn(acc2[i][2], acc2[i][3]);
                ((float2*)(out2 + (size_t)gr * D))[cg] = o2;
            }
        }
    }
}

// ================= SAGE epilogue: h2 = relu( agg(A)/deg + B ), masked-unrolled =================

__global__ __launch_bounds__(256) void sage_agg_kernel(const int* __restrict__ rowptr,
                                                       const int* __restrict__ col,
                                                       const __half* __restrict__ A,
                                                       const __half* __restrict__ B,
                                                       __half* __restrict__ h2, int N) {
    int tid = threadIdx.x;
    int lane = tid & 63;
    int grp = lane >> 4, li = lane & 15;
    int v = blockIdx.x * 4 + (tid >> 6);
    if (v >= N) return;
    int beg = rowptr[v], end = rowptr[v + 1];
    float a0 = 0.f, a1 = 0.f, a2 = 0.f, a3 = 0.f;
    for (int e0 = beg; e0 < end; e0 += 16) {
#pragma unroll
        for (int j = 0; j < 4; ++j) {
            int e = e0 + 4 * j + grp;
            float m = (e < end) ? 1.f : 0.f;
            int ec = (e < end) ? e : (end - 1);
            int u = col[ec] & 0xFFFF;
            float2 r = *((const float2*)(A + (size_t)u * D) + li);
            float2 f01 = __half22float2(*(const __half2*)&r.x);
            float2 f23 = __half22float2(*(const __half2*)&r.y);
            a0 += m * f01.x; a1 += m * f01.y; a2 += m * f23.x; a3 += m * f23.y;
        }
    }
    a0 += __shfl_xor(a0, 16); a0 += __shfl_xor(a0, 32);
    a1 += __shfl_xor(a1, 16); a1 += __shfl_xor(a1, 32);
    a2 += __shfl_xor(a2, 16); a2 += __shfl_xor(a2, 32);
    a3 += __shfl_xor(a3, 16); a3 += __shfl_xor(a3, 32);
    if (grp == 0) {
        float inv = 1.f / fmaxf((float)(end - beg), 1.f);
        float2 br = *((const float2*)(B + (size_t)v * D) + li);
        float2 b01 = __half22float2(*(const __half2*)&br.x);
        float2 b23 = __half22float2(*(const __half2*)&br.y);
        float2 oh;
        *(__half2*)&oh.x = __floats2half2_rn(fmaxf(a0 * inv + b01.x, 0.f),
                                             fmaxf(a1 * inv + b01.y, 0.f));
        *(__half2*)&oh.y = __floats2half2_rn(fmaxf(a2 * inv + b23.x, 0.f),
                                             fmaxf(a3 * inv + b23.y, 0.f));
        ((float2*)(h2 + (size_t)v * D))[li] = oh;
    }
}

// ================= GIN epilogue: t = relu( C + agg(C) + b1 ), masked-unrolled =================

__global__ __launch_bounds__(256) void gin_agg_kernel(const int* __restrict__ rowptr,
                                                      const int* __restrict__ col,
                                                      const __half* __restrict__ C,
                                                      const float* __restrict__ b1,
                                                      __half* __restrict__ t, int N) {
    int tid = threadIdx.x;
    int lane = tid & 63;
    int grp = lane >> 4, li = lane & 15;
    int v = blockIdx.x * 4 + (tid >> 6);
    if (v >= N) return;
    int beg = rowptr[v], end = rowptr[v + 1];
    float a0 = 0.f, a1 = 0.f, a2 = 0.f, a3 = 0.f;
    for (int e0 = beg; e0 < end; e0 += 16) {
#pragma unroll
        for (int j = 0; j < 4; ++j) {
            int e = e0 + 4 * j + grp;
            float m = (e < end) ? 1.f : 0.f;
            int ec = (e < end) ? e : (end - 1);
            int u = col[ec] & 0xFFFF;
            float2 r = *((const float2*)(C + (size_t)u * D) + li);
            float2 f01 = __half22float2(*(const __half2*)&r.x);
            float2 f23 = __half22float2(*(const __half2*)&r.y);
            a0 += m * f01.x; a1 += m * f01.y; a2 += m * f23.x; a3 += m * f23.y;
        }
    }
    a0 += __shfl_xor(a0, 16); a0 += __shfl_xor(a0, 32);
    a1 += __shfl_xor(a1, 16); a1 += __shfl_xor(a1, 32);
    a2 += __shfl_xor(a2, 16); a2 += __shfl_xor(a2, 32);
    a3 += __shfl_xor(a3, 16); a3 += __shfl_xor(a3, 32);
    if (grp == 0) {
        float2 rs = *((const float2*)(C + (size_t)v * D) + li);   // self term
        float2 s01 = __half22float2(*(const __half2*)&rs.x);
        float2 s23 = __half22float2(*(const __half2*)&rs.y);
        float4 bb = ((const float4*)b1)[li];
        float2 oh;
        *(__half2*)&oh.x = __floats2half2_rn(fmaxf(s01.x + a0 + bb.x, 0.f),
                                             fmaxf(s01.y + a1 + bb.y, 0.f));
        *(__half2*)&oh.y = __floats2half2_rn(fmaxf(s23.x + a2 + bb.z, 0.f),
                                             fmaxf(s23.y + a3 + bb.w, 0.f));
        ((float2*)(t + (size_t)v * D))[li] = oh;
    }
}

// ================= pooling: 16 waves per graph + LDS tree reduce (fp16 inputs) =================

__global__ __launch_bounds__(1024) void pool_final_kernel(
    const __half* __restrict__ h1, const __half* __restrict__ h2,
    const __half* __restrict__ h3,
    const int* __restrict__ batch, int N,
    const float* __restrict__ W1, const float* __restrict__ W2,
    const float* __restrict__ W3, float* __restrict__ out, int G) {
    __shared__ float r1[16][64];
    __shared__ float r2[16][64];
    __shared__ float r3[16][64];
    int g = blockIdx.x;
    int tid = threadIdx.x;
    int w = tid >> 6, lane = tid & 63;

    int lo = 0, hi = N;
    while (lo < hi) { int mid = (lo + hi) >> 1; if (batch[mid] < g) lo = mid + 1; else hi = mid; }
    int beg = lo;
    hi = N;
    while (lo < hi) { int mid = (lo + hi) >> 1; if (batch[mid] < g + 1) lo = mid + 1; else hi = mid; }
    int end = lo;

    float s1 = 0.f, s2 = 0.f, s3 = 0.f;
    for (int v = beg + w; v < end; v += 16) {
        size_t idx = (size_t)v * D + lane;
        s1 += __half2float(h1[idx]);
        s2 += __half2float(h2[idx]);
        s3 += __half2float(h3[idx]);
    }
    r1[w][lane] = s1; r2[w][lane] = s2; r3[w][lane] = s3;
    __syncthreads();
#pragma unroll
    for (int stride = 8; stride >= 1; stride >>= 1) {
        if (w < stride) {
            r1[w][lane] += r1[w + stride][lane];
            r2[w][lane] += r2[w + stride][lane];
            r3[w][lane] += r3[w + stride][lane];
        }
        __syncthreads();
    }
    if (w == 0) {
        float inv = 1.f / fmaxf((float)(end - beg), 1.f);
        float p1 = r1[0][lane] * inv, p2 = r2[0][lane] * inv, p3 = r3[0][lane] * inv;
        float acc = 0.f;
#pragma unroll
        for (int k = 0; k < D; ++k) {
            acc += __shfl(p1, k) * W1[k * D + lane]
                 + __shfl(p2, k) * W2[k * D + lane]
                 + __shfl(p3, k) * W3[k * D + lane];
        }
        out[(size_t)g * D + lane] = fmaxf(acc, 0.f);
    }
}

// ================= launch =================

static inline size_t align256(size_t x) { return (x + 255) & ~(size_t)255; }

extern "C" void kernel_launch(void* const* d_in, const int* in_sizes, int n_in,
                              void* d_out, int out_size, void* d_ws, size_t ws_size,
                              hipStream_t stream) {
    const int* x      = (const int*)d_in[0];
    const int* ei     = (const int*)d_in[1];
    const int* batch  = (const int*)d_in[2];
    const float* emb  = (const float*)d_in[3];
    const float* Wgcn = (const float*)d_in[4];
    const float* Wsl  = (const float*)d_in[5];
    const float* Wsr  = (const float*)d_in[6];
    const float* Wg1  = (const float*)d_in[7];
    const float* bg1  = (const float*)d_in[8];
    const float* Wg2  = (const float*)d_in[9];
    const float* bg2  = (const float*)d_in[10];
    const float* Wp1  = (const float*)d_in[11];
    const float* Wp2  = (const float*)d_in[12];
    const float* Wp3  = (const float*)d_in[13];
    float* out = (float*)d_out;

    const int N = in_sizes[0];
    const int E = in_sizes[1] / 2;
    const int V = in_sizes[3] / D;
    const int G = out_size / D;
    const int* src = ei;
    const int* dst = ei + E;
    const int NBUCK = (N + 255) >> 8;

    // workspace layout
    char* base = (char*)d_ws;
    size_t off = 0;
    float* embW    = (float*)(base + off); off = align256(off + (size_t)V * D * 4);
    int* bucketCount  = (int*)(base + off); off = align256(off + 256 * 4);
    int* bucketBase   = (int*)(base + off); off = align256(off + 257 * 4);
    int* bucketCursor = (int*)(base + off); off = align256(off + 256 * 4);
    int* rowptr    = (int*)(base + off);   off = align256(off + (size_t)(N + 1) * 4);
    int* ebuf      = (int*)(base + off);   off = align256(off + (size_t)E * 4);
    int* col       = (int*)(base + off);   off = align256(off + (size_t)E * 4);
    __half* h1     = (__half*)(base + off); off = align256(off + (size_t)N * D * 2);
    __half* h2     = (__half*)(base + off); off = align256(off + (size_t)N * D * 2);
    __half* h3     = (__half*)(base + off); off = align256(off + (size_t)N * D * 2);
    __half* Ah     = (__half*)(base + off); off = align256(off + (size_t)N * D * 2);
    __half* B      = (__half*)(base + off); off = align256(off + (size_t)N * D * 2);
    (void)ws_size;

    __half* Ch = Ah;  // reuse: Ah dead after sage_agg
    __half* t  = B;   // reuse: B dead after sage_agg

    hipMemsetAsync(bucketCount, 0, 256 * 4, stream);

    // embW = emb @ Wgcn (fp32, tiny, separate low-pressure kernel)
    gemm64_kernel<<<(V + 63) / 64, 256, 0, stream>>>(emb, V, Wgcn, embW);

    // CSR build front-end
    bucket_count_kernel<<<256, 256, 0, stream>>>(dst, E, bucketCount);
    bucket_scan_kernel<<<1, 256, 0, stream>>>(bucketCount, bucketBase, bucketCursor);
    scatter_kernel<<<(E + K3E - 1) / K3E, 256, 0, stream>>>(src, dst, x, bucketCursor, ebuf, E);

    // fused CSR finalize + GCN gather -> rowptr, col, h1 (fp16)
    csr_gcn_kernel<<<NBUCK, 1024, 0, stream>>>(ebuf, bucketBase, embW, rowptr, col, h1, N, E, V);

    // SAGE: Ah = fp16(h1@Wl), B = fp16(h1@Wr), then fused agg epilogue -> h2 (fp16)
    int gb = (N + 63) / 64;
    gemm64h_kernel<<<gb, 256, 0, stream>>>(h1, N, Wsl, Wsr, nullptr, 0, Ah, B);
    sage_agg_kernel<<<(N + 3) / 4, 256, 0, stream>>>(rowptr, col, Ah, B, h2, N);

    // GIN: Ch = fp16(h2@W1), t = relu(C + agg(C) + b1), h3 = fp16(relu(t@W2 + b2))
    gemm64h_kernel<<<gb, 256, 0, stream>>>(h2, N, Wg1, nullptr, nullptr, 0, Ch, nullptr);
    gin_agg_kernel<<<(N + 3) / 4, 256, 0, stream>>>(rowptr, col, Ch, bg1, t, N);
    gemm64h_kernel<<<gb, 256, 0, stream>>>(t, N, Wg2, nullptr, bg2, 1, h3, nullptr);

    // pooling (16 waves/graph, LDS reduce)
    pool_final_kernel<<<G, 1024, 0, stream>>>(h1, h2, h3, batch, N, Wp1, Wp2, Wp3, out, G);
}

// Round 11
// 255.815 us; speedup vs baseline: 1.0571x; 1.0095x over previous
//
#include <hip/hip_runtime.h>
#include <hip/hip_bf16.h>
#include <hip/hip_fp16.h>

#define D 64
#define K3E 4096
#define ECAP 6144   // max edges per 256-node bucket held in LDS (mean 4082, sigma 64 -> 32 sigma)

// Edge word packing (requires N <= 65536, V <= 128 — true for this problem):
//   bits [0:15]  = src node
//   bits [16:22] = x[src]   (vocab id)
//   bits [23:30] = dst & 255 (node index within its 256-node bucket)

// ================= fp32 GEMM (used once for embW, V=128 rows) =================

__global__ __launch_bounds__(256) void gemm64_kernel(
    const float* __restrict__ in, int nrows,
    const float* __restrict__ W1,
    float* __restrict__ out1)
{
    __shared__ float At[64][68];
    __shared__ float Ws1[64][64];
    int tid = threadIdx.x;
    {
        const float4* w1v = (const float4*)W1;
        float4* s1 = (float4*)&Ws1[0][0];
        for (int i = tid; i < 1024; i += 256) s1[i] = w1v[i];
    }
    int r0 = blockIdx.x * 64;
    for (int i = tid; i < 1024; i += 256) {
        int r = i >> 4, c4 = i & 15;
        int gr = r0 + r; if (gr >= nrows) gr = nrows - 1;
        float4 v = ((const float4*)(in + (size_t)gr * D))[c4];
        float* dp = &At[r][c4 * 4];
        dp[0] = v.x; dp[1] = v.y; dp[2] = v.z; dp[3] = v.w;
    }
    __syncthreads();

    int cg = tid & 15;
    int rg = tid >> 4;
    float acc1[4][4] = {{0.f}};

    for (int k0 = 0; k0 < 64; k0 += 4) {
        float4 a[4], w1[4];
#pragma unroll
        for (int i = 0; i < 4; ++i) a[i] = *(const float4*)&At[4 * rg + i][k0];
#pragma unroll
        for (int j = 0; j < 4; ++j) w1[j] = *(const float4*)&Ws1[k0 + j][cg * 4];
#pragma unroll
        for (int i = 0; i < 4; ++i) {
            float av[4] = {a[i].x, a[i].y, a[i].z, a[i].w};
#pragma unroll
            for (int kk = 0; kk < 4; ++kk) {
                acc1[i][0] += av[kk] * w1[kk].x;
                acc1[i][1] += av[kk] * w1[kk].y;
                acc1[i][2] += av[kk] * w1[kk].z;
                acc1[i][3] += av[kk] * w1[kk].w;
            }
        }
    }
#pragma unroll
    for (int i = 0; i < 4; ++i) {
        int gr = r0 + 4 * rg + i;
        if (gr < nrows) {
            float4 o;
            o.x = acc1[i][0]; o.y = acc1[i][1]; o.z = acc1[i][2]; o.w = acc1[i][3];
            ((float4*)(out1 + (size_t)gr * D))[cg] = o;
        }
    }
}

// ================= bucketed CSR build (low-VGPR front-end) =================

__global__ __launch_bounds__(256) void bucket_count_kernel(const int* __restrict__ dst, int E,
                                                           int* __restrict__ bucketCount) {
    __shared__ int hist[256];
    int t = threadIdx.x;
    hist[t] = 0;
    __syncthreads();
    for (int e = blockIdx.x * 256 + t; e < E; e += gridDim.x * 256)
        atomicAdd(&hist[dst[e] >> 8], 1);
    __syncthreads();
    int c = hist[t];
    if (c) atomicAdd(&bucketCount[t], c);
}

__global__ void bucket_scan_kernel(const int* __restrict__ bucketCount,
                                   int* __restrict__ bucketBase, int* __restrict__ bucketCursor) {
    __shared__ int lds[256];
    int t = threadIdx.x;
    int c = bucketCount[t];
    lds[t] = c;
    __syncthreads();
    for (int off = 1; off < 256; off <<= 1) {
        int v = (t >= off) ? lds[t - off] : 0;
        __syncthreads();
        lds[t] += v;
        __syncthreads();
    }
    int excl = lds[t] - c;
    bucketBase[t] = excl;
    bucketCursor[t] = excl;
    if (t == 255) bucketBase[256] = lds[t];
}

__global__ __launch_bounds__(256) void scatter_kernel(const int* __restrict__ src,
                                                      const int* __restrict__ dst,
                                                      const int* __restrict__ x,
                                                      int* __restrict__ bucketCursor,
                                                      int* __restrict__ ebuf, int E) {
    __shared__ int uu[K3E];
    __shared__ unsigned char bb[K3E];
    __shared__ int hist[256];
    __shared__ int resBase[256];
    int t = threadIdx.x;
    hist[t] = 0;
    __syncthreads();
    int e0 = blockIdx.x * K3E;
    int cnt = E - e0; if (cnt > K3E) cnt = K3E;
    for (int i = t; i < cnt; i += 256) {
        int e = e0 + i;
        int s = src[e];
        int d = dst[e];
        int xs = x[s];
        uu[i] = s | (xs << 16) | ((d & 255) << 23);
        int b = d >> 8;
        bb[i] = (unsigned char)b;
        atomicAdd(&hist[b], 1);
    }
    __syncthreads();
    int c = hist[t];
    if (c) resBase[t] = atomicAdd(&bucketCursor[t], c);
    __syncthreads();
    hist[t] = 0;
    __syncthreads();
    for (int i = t; i < cnt; i += 256) {
        int b = bb[i];
        int r = atomicAdd(&hist[b], 1);
        ebuf[resBase[b] + r] = uu[i];
    }
}

// ===== fused: per-bucket exact CSR + GCN gather (h1), 8 LDS loads in flight =====

__global__ __launch_bounds__(1024) void csr_gcn_kernel(
    const int* __restrict__ ebuf, const int* __restrict__ bucketBase,
    const float* __restrict__ embW,
    int* __restrict__ rowptr, int* __restrict__ col,
    __half* __restrict__ h1, int N, int E, int V)
{
    __shared__ int   eLds[ECAP];       // 24 KB
    __shared__ float lembW[128 * D];   // 32 KB (V<=128)
    __shared__ int   hist[256];        // 1 KB
    __shared__ int   sc[256];          // 1 KB
    __shared__ int   begS[256];        // 1 KB
    int b = blockIdx.x, t = threadIdx.x;
    int base = bucketBase[b], endb = bucketBase[b + 1];
    int m = endb - base;
    bool useLds = (m <= ECAP);

    for (int i = t; i < V * D; i += 1024) lembW[i] = embW[i];
    if (t < 256) hist[t] = 0;
    __syncthreads();

    for (int i = t; i < m; i += 1024) {
        int u = ebuf[base + i];
        if (useLds) eLds[i] = u;
        atomicAdd(&hist[(u >> 23) & 255], 1);
    }
    __syncthreads();

    int v = (t < 256) ? hist[t] : 0;
    if (t < 256) sc[t] = v;
    __syncthreads();
    for (int off = 1; off < 256; off <<= 1) {
        int w = (t >= off && t < 256) ? sc[t - off] : 0;
        __syncthreads();
        if (t < 256) sc[t] += w;
        __syncthreads();
    }
    if (t < 256) {
        int excl = sc[t] - v;
        begS[t] = excl;
        int node = (b << 8) + t;
        if (node < N) rowptr[node] = base + excl;
        hist[t] = excl;   // running local cursor
    }
    if (b == gridDim.x - 1 && t == 0) rowptr[N] = E;
    __syncthreads();

    for (int i = t; i < m; i += 1024) {
        int u = useLds ? eLds[i] : ebuf[base + i];
        int dl = (u >> 23) & 255;
        int r = atomicAdd(&hist[dl], 1);
        col[base + r] = u;
    }
    __syncthreads();

    // phase B: GCN gather, 16-edge masked unroll (8 LDS loads in flight)
    int w = t >> 6, lane = t & 63;
    int g2 = lane >> 5, lj = lane & 31;
    for (int i = 0; i < 16; ++i) {
        int nt = w * 16 + i;
        int node = (b << 8) + nt;
        if (node >= N) break;
        int beg = base + begS[nt], end = base + sc[nt];
        float ax = 0.f, ay = 0.f;
        for (int e0 = beg; e0 < end; e0 += 16) {
#pragma unroll
            for (int j = 0; j < 8; ++j) {
                int e = e0 + 2 * j + g2;
                float mm = (e < end) ? 1.f : 0.f;
                int ec = (e < end) ? e : (end - 1);
                int xu = (col[ec] >> 16) & 0x7F;
                float2 f = *((const float2*)(lembW + xu * D) + lj);
                ax += mm * f.x; ay += mm * f.y;
            }
        }
        ax += __shfl_xor(ax, 32);
        ay += __shfl_xor(ay, 32);
        if (g2 == 0)
            ((__half2*)(h1 + (size_t)node * D))[lj] =
                __floats2half2_rn(fmaxf(ax, 0.f), fmaxf(ay, 0.f));
    }
}

// ===== fp16-in / fp16-out GEMM (fp32 LDS + fp32 accumulate), optional dual output =====

__global__ __launch_bounds__(256) void gemm64h_kernel(
    const __half* __restrict__ in, int nrows,
    const float* __restrict__ W1, const float* __restrict__ W2,
    const float* __restrict__ bias, int do_relu,
    __half* __restrict__ out1, __half* __restrict__ out2)
{
    __shared__ float At[64][68];
    __shared__ float Ws1[64][64];
    __shared__ float Ws2[64][64];
    int tid = threadIdx.x;
    {
        const float4* w1v = (const float4*)W1;
        float4* s1 = (float4*)&Ws1[0][0];
        for (int i = tid; i < 1024; i += 256) s1[i] = w1v[i];
        if (W2) {
            const float4* w2v = (const float4*)W2;
            float4* s2 = (float4*)&Ws2[0][0];
            for (int i = tid; i < 1024; i += 256) s2[i] = w2v[i];
        }
    }
    int r0 = blockIdx.x * 64;
    for (int i = tid; i < 512; i += 256) {
        int r = i >> 3, c8 = i & 7;
        int gr = r0 + r; if (gr >= nrows) gr = nrows - 1;
        float4 hv = ((const float4*)(in + (size_t)gr * D))[c8];
        const __half2* hp = (const __half2*)&hv;
        float* dp = &At[r][c8 * 8];
        float2 f;
        f = __half22float2(hp[0]); dp[0] = f.x; dp[1] = f.y;
        f = __half22float2(hp[1]); dp[2] = f.x; dp[3] = f.y;
        f = __half22float2(hp[2]); dp[4] = f.x; dp[5] = f.y;
        f = __half22float2(hp[3]); dp[6] = f.x; dp[7] = f.y;
    }
    __syncthreads();

    int cg = tid & 15;
    int rg = tid >> 4;
    float acc1[4][4] = {{0.f}}, acc2[4][4] = {{0.f}};

    for (int k0 = 0; k0 < 64; k0 += 4) {
        float4 a[4], w1[4];
#pragma unroll
        for (int i = 0; i < 4; ++i) a[i] = *(const float4*)&At[4 * rg + i][k0];
#pragma unroll
        for (int j = 0; j < 4; ++j) w1[j] = *(const float4*)&Ws1[k0 + j][cg * 4];
#pragma unroll
        for (int i = 0; i < 4; ++i) {
            float av[4] = {a[i].x, a[i].y, a[i].z, a[i].w};
#pragma unroll
            for (int kk = 0; kk < 4; ++kk) {
                acc1[i][0] += av[kk] * w1[kk].x;
                acc1[i][1] += av[kk] * w1[kk].y;
                acc1[i][2] += av[kk] * w1[kk].z;
                acc1[i][3] += av[kk] * w1[kk].w;
            }
        }
        if (W2) {
            float4 w2[4];
#pragma unroll
            for (int j = 0; j < 4; ++j) w2[j] = *(const float4*)&Ws2[k0 + j][cg * 4];
#pragma unroll
            for (int i = 0; i < 4; ++i) {
                float av[4] = {a[i].x, a[i].y, a[i].z, a[i].w};
#pragma unroll
                for (int kk = 0; kk < 4; ++kk) {
                    acc2[i][0] += av[kk] * w2[kk].x;
                    acc2[i][1] += av[kk] * w2[kk].y;
                    acc2[i][2] += av[kk] * w2[kk].z;
                    acc2[i][3] += av[kk] * w2[kk].w;
                }
            }
        }
    }

    float4 bv = make_float4(0.f, 0.f, 0.f, 0.f);
    if (bias) bv = ((const float4*)bias)[cg];
#pragma unroll
    for (int i = 0; i < 4; ++i) {
        int gr = r0 + 4 * rg + i;
        if (gr < nrows) {
            float ox = acc1[i][0] + bv.x, oy = acc1[i][1] + bv.y;
            float oz = acc1[i][2] + bv.z, ow = acc1[i][3] + bv.w;
            if (do_relu) {
                ox = fmaxf(ox, 0.f); oy = fmaxf(oy, 0.f);
                oz = fmaxf(oz, 0.f); ow = fmaxf(ow, 0.f);
            }
            float2 oh;
            *(__half2*)&oh.x = __floats2half2_rn(ox, oy);
            *(__half2*)&oh.y = __floats2half2_rn(oz, ow);
            ((float2*)(out1 + (size_t)gr * D))[cg] = oh;
            if (out2) {
                float2 o2;
                *(__half2*)&o2.x = __floats2half2_rn(acc2[i][0], acc2[i][1]);
                *(__half2*)&o2.y = __floats2half2_rn(acc2[i][2], acc2[i][3]);
                ((float2*)(out2 + (size_t)gr * D))[cg] = o2;
            }
        }
    }
}

// ===== SAGE epilogue: h2 = relu( agg(A)/deg + B ), 32-edge masked unroll =====

__global__ __launch_bounds__(256) void sage_agg_kernel(const int* __restrict__ rowptr,
                                                       const int* __restrict__ col,
                                                       const __half* __restrict__ A,
                                                       const __half* __restrict__ B,
                                                       __half* __restrict__ h2, int N) {
    int tid = threadIdx.x;
    int lane = tid & 63;
    int grp = lane >> 4, li = lane & 15;
    int v = blockIdx.x * 4 + (tid >> 6);
    if (v >= N) return;
    int beg = rowptr[v], end = rowptr[v + 1];
    float a0 = 0.f, a1 = 0.f, a2 = 0.f, a3 = 0.f;
    for (int e0 = beg; e0 < end; e0 += 32) {
#pragma unroll
        for (int j = 0; j < 8; ++j) {
            int e = e0 + 4 * j + grp;
            float m = (e < end) ? 1.f : 0.f;
            int ec = (e < end) ? e : (end - 1);
            int u = col[ec] & 0xFFFF;
            float2 r = *((const float2*)(A + (size_t)u * D) + li);
            float2 f01 = __half22float2(*(const __half2*)&r.x);
            float2 f23 = __half22float2(*(const __half2*)&r.y);
            a0 += m * f01.x; a1 += m * f01.y; a2 += m * f23.x; a3 += m * f23.y;
        }
    }
    a0 += __shfl_xor(a0, 16); a0 += __shfl_xor(a0, 32);
    a1 += __shfl_xor(a1, 16); a1 += __shfl_xor(a1, 32);
    a2 += __shfl_xor(a2, 16); a2 += __shfl_xor(a2, 32);
    a3 += __shfl_xor(a3, 16); a3 += __shfl_xor(a3, 32);
    if (grp == 0) {
        float inv = 1.f / fmaxf((float)(end - beg), 1.f);
        float2 br = *((const float2*)(B + (size_t)v * D) + li);
        float2 b01 = __half22float2(*(const __half2*)&br.x);
        float2 b23 = __half22float2(*(const __half2*)&br.y);
        float2 oh;
        *(__half2*)&oh.x = __floats2half2_rn(fmaxf(a0 * inv + b01.x, 0.f),
                                             fmaxf(a1 * inv + b01.y, 0.f));
        *(__half2*)&oh.y = __floats2half2_rn(fmaxf(a2 * inv + b23.x, 0.f),
                                             fmaxf(a3 * inv + b23.y, 0.f));
        ((float2*)(h2 + (size_t)v * D))[li] = oh;
    }
}

// ===== GIN epilogue: t = relu( C + agg(C) + b1 ), 32-edge masked unroll =====

__global__ __launch_bounds__(256) void gin_agg_kernel(const int* __restrict__ rowptr,
                                                      const int* __restrict__ col,
                                                      const __half* __restrict__ C,
                                                      const float* __restrict__ b1,
                                                      __half* __restrict__ t, int N) {
    int tid = threadIdx.x;
    int lane = tid & 63;
    int grp = lane >> 4, li = lane & 15;
    int v = blockIdx.x * 4 + (tid >> 6);
    if (v >= N) return;
    int beg = rowptr[v], end = rowptr[v + 1];
    float a0 = 0.f, a1 = 0.f, a2 = 0.f, a3 = 0.f;
    for (int e0 = beg; e0 < end; e0 += 32) {
#pragma unroll
        for (int j = 0; j < 8; ++j) {
            int e = e0 + 4 * j + grp;
            float m = (e < end) ? 1.f : 0.f;
            int ec = (e < end) ? e : (end - 1);
            int u = col[ec] & 0xFFFF;
            float2 r = *((const float2*)(C + (size_t)u * D) + li);
            float2 f01 = __half22float2(*(const __half2*)&r.x);
            float2 f23 = __half22float2(*(const __half2*)&r.y);
            a0 += m * f01.x; a1 += m * f01.y; a2 += m * f23.x; a3 += m * f23.y;
        }
    }
    a0 += __shfl_xor(a0, 16); a0 += __shfl_xor(a0, 32);
    a1 += __shfl_xor(a1, 16); a1 += __shfl_xor(a1, 32);
    a2 += __shfl_xor(a2, 16); a2 += __shfl_xor(a2, 32);
    a3 += __shfl_xor(a3, 16); a3 += __shfl_xor(a3, 32);
    if (grp == 0) {
        float2 rs = *((const float2*)(C + (size_t)v * D) + li);   // self term
        float2 s01 = __half22float2(*(const __half2*)&rs.x);
        float2 s23 = __half22float2(*(const __half2*)&rs.y);
        float4 bb = ((const float4*)b1)[li];
        float2 oh;
        *(__half2*)&oh.x = __floats2half2_rn(fmaxf(s01.x + a0 + bb.x, 0.f),
                                             fmaxf(s01.y + a1 + bb.y, 0.f));
        *(__half2*)&oh.y = __floats2half2_rn(fmaxf(s23.x + a2 + bb.z, 0.f),
                                             fmaxf(s23.y + a3 + bb.w, 0.f));
        ((float2*)(t + (size_t)v * D))[li] = oh;
    }
}

// ===== pooling: 16 waves/graph, half2 reads, row-parity split + LDS tree reduce =====

__global__ __launch_bounds__(1024) void pool_final_kernel(
    const __half* __restrict__ h1, const __half* __restrict__ h2,
    const __half* __restrict__ h3,
    const int* __restrict__ batch, int N,
    const float* __restrict__ W1, const float* __restrict__ W2,
    const float* __restrict__ W3, float* __restrict__ out, int G) {
    __shared__ float r1[16][64];
    __shared__ float r2[16][64];
    __shared__ float r3[16][64];
    int g = blockIdx.x;
    int tid = threadIdx.x;
    int w = tid >> 6, lane = tid & 63;
    int half = lane >> 5, lc = lane & 31;   // lane covers cols 2lc,2lc+1 of row-parity `half`

    int lo = 0, hi = N;
    while (lo < hi) { int mid = (lo + hi) >> 1; if (batch[mid] < g) lo = mid + 1; else hi = mid; }
    int beg = lo;
    hi = N;
    while (lo < hi) { int mid = (lo + hi) >> 1; if (batch[mid] < g + 1) lo = mid + 1; else hi = mid; }
    int end = lo;

    float s1x = 0.f, s1y = 0.f, s2x = 0.f, s2y = 0.f, s3x = 0.f, s3y = 0.f;
    for (int v = beg + 2 * w + half; v < end; v += 32) {
        size_t ro = (size_t)v * D;
        float2 f1 = __half22float2(((const __half2*)(h1 + ro))[lc]);
        float2 f2 = __half22float2(((const __half2*)(h2 + ro))[lc]);
        float2 f3 = __half22float2(((const __half2*)(h3 + ro))[lc]);
        s1x += f1.x; s1y += f1.y;
        s2x += f2.x; s2y += f2.y;
        s3x += f3.x; s3y += f3.y;
    }
    // combine row parities (lane ^ 32 holds the other parity, same columns)
    s1x += __shfl_xor(s1x, 32); s1y += __shfl_xor(s1y, 32);
    s2x += __shfl_xor(s2x, 32); s2y += __shfl_xor(s2y, 32);
    s3x += __shfl_xor(s3x, 32); s3y += __shfl_xor(s3y, 32);
    if (half == 0) {
        ((float2*)r1[w])[lc] = make_float2(s1x, s1y);
        ((float2*)r2[w])[lc] = make_float2(s2x, s2y);
        ((float2*)r3[w])[lc] = make_float2(s3x, s3y);
    }
    __syncthreads();
#pragma unroll
    for (int stride = 8; stride >= 1; stride >>= 1) {
        if (w < stride) {
            r1[w][lane] += r1[w + stride][lane];
            r2[w][lane] += r2[w + stride][lane];
            r3[w][lane] += r3[w + stride][lane];
        }
        __syncthreads();
    }
    if (w == 0) {
        float inv = 1.f / fmaxf((float)(end - beg), 1.f);
        float p1 = r1[0][lane] * inv, p2 = r2[0][lane] * inv, p3 = r3[0][lane] * inv;
        float acc = 0.f;
#pragma unroll
        for (int k = 0; k < D; ++k) {
            acc += __shfl(p1, k) * W1[k * D + lane]
                 + __shfl(p2, k) * W2[k * D + lane]
                 + __shfl(p3, k) * W3[k * D + lane];
        }
        out[(size_t)g * D + lane] = fmaxf(acc, 0.f);
    }
}

// ================= launch =================

static inline size_t align256(size_t x) { return (x + 255) & ~(size_t)255; }

extern "C" void kernel_launch(void* const* d_in, const int* in_sizes, int n_in,
                              void* d_out, int out_size, void* d_ws, size_t ws_size,
                              hipStream_t stream) {
    const int* x      = (const int*)d_in[0];
    const int* ei     = (const int*)d_in[1];
    const int* batch  = (const int*)d_in[2];
    const float* emb  = (const float*)d_in[3];
    const float* Wgcn = (const float*)d_in[4];
    const float* Wsl  = (const float*)d_in[5];
    const float* Wsr  = (const float*)d_in[6];
    const float* Wg1  = (const float*)d_in[7];
    const float* bg1  = (const float*)d_in[8];
    const float* Wg2  = (const float*)d_in[9];
    const float* bg2  = (const float*)d_in[10];
    const float* Wp1  = (const float*)d_in[11];
    const float* Wp2  = (const float*)d_in[12];
    const float* Wp3  = (const float*)d_in[13];
    float* out = (float*)d_out;

    const int N = in_sizes[0];
    const int E = in_sizes[1] / 2;
    const int V = in_sizes[3] / D;
    const int G = out_size / D;
    const int* src = ei;
    const int* dst = ei + E;
    const int NBUCK = (N + 255) >> 8;

    // workspace layout
    char* base = (char*)d_ws;
    size_t off = 0;
    float* embW    = (float*)(base + off); off = align256(off + (size_t)V * D * 4);
    int* bucketCount  = (int*)(base + off); off = align256(off + 256 * 4);
    int* bucketBase   = (int*)(base + off); off = align256(off + 257 * 4);
    int* bucketCursor = (int*)(base + off); off = align256(off + 256 * 4);
    int* rowptr    = (int*)(base + off);   off = align256(off + (size_t)(N + 1) * 4);
    int* ebuf      = (int*)(base + off);   off = align256(off + (size_t)E * 4);
    int* col       = (int*)(base + off);   off = align256(off + (size_t)E * 4);
    __half* h1     = (__half*)(base + off); off = align256(off + (size_t)N * D * 2);
    __half* h2     = (__half*)(base + off); off = align256(off + (size_t)N * D * 2);
    __half* h3     = (__half*)(base + off); off = align256(off + (size_t)N * D * 2);
    __half* Ah     = (__half*)(base + off); off = align256(off + (size_t)N * D * 2);
    __half* B      = (__half*)(base + off); off = align256(off + (size_t)N * D * 2);
    (void)ws_size;

    __half* Ch = Ah;  // reuse: Ah dead after sage_agg
    __half* t  = B;   // reuse: B dead after sage_agg

    hipMemsetAsync(bucketCount, 0, 256 * 4, stream);

    // embW = emb @ Wgcn (fp32, tiny, separate low-pressure kernel)
    gemm64_kernel<<<(V + 63) / 64, 256, 0, stream>>>(emb, V, Wgcn, embW);

    // CSR build front-end
    bucket_count_kernel<<<256, 256, 0, stream>>>(dst, E, bucketCount);
    bucket_scan_kernel<<<1, 256, 0, stream>>>(bucketCount, bucketBase, bucketCursor);
    scatter_kernel<<<(E + K3E - 1) / K3E, 256, 0, stream>>>(src, dst, x, bucketCursor, ebuf, E);

    // fused CSR finalize + GCN gather -> rowptr, col, h1 (fp16)
    csr_gcn_kernel<<<NBUCK, 1024, 0, stream>>>(ebuf, bucketBase, embW, rowptr, col, h1, N, E, V);

    // SAGE: Ah = fp16(h1@Wl), B = fp16(h1@Wr), then fused agg epilogue -> h2 (fp16)
    int gb = (N + 63) / 64;
    gemm64h_kernel<<<gb, 256, 0, stream>>>(h1, N, Wsl, Wsr, nullptr, 0, Ah, B);
    sage_agg_kernel<<<(N + 3) / 4, 256, 0, stream>>>(rowptr, col, Ah, B, h2, N);

    // GIN: Ch = fp16(h2@W1), t = relu(C + agg(C) + b1), h3 = fp16(relu(t@W2 + b2))
    gemm64h_kernel<<<gb, 256, 0, stream>>>(h2, N, Wg1, nullptr, nullptr, 0, Ch, nullptr);
    gin_agg_kernel<<<(N + 3) / 4, 256, 0, stream>>>(rowptr, col, Ch, bg1, t, N);
    gemm64h_kernel<<<gb, 256, 0, stream>>>(t, N, Wg2, nullptr, bg2, 1, h3, nullptr);

    // pooling (16 waves/graph, half2 reads, LDS reduce)
    pool_final_kernel<<<G, 1024, 0, stream>>>(h1, h2, h3, batch, N, Wp1, Wp2, Wp3, out, G);
}